// Round 15
// baseline (324.013 us; speedup 1.0000x reference)
//
#include <hip/hip_runtime.h>
#include <hip/hip_bf16.h>

#define B_   2
#define N_   384
#define DIM_ 256
#define H_   4
#define DH_  64
#define PD_  128
#define ED_  16
#define NT_  24                 // j-tiles per row (N_/16)
#define TPB_ 300                // upper-tri tiles per batch: 24*25/2
#define JOBS_ 600               // total tile jobs (B_ * TPB_)

typedef _Float16 v8h __attribute__((ext_vector_type(8)));
typedef float    v4f __attribute__((ext_vector_type(4)));

__device__ __forceinline__ float rcp_(float x) { return __builtin_amdgcn_rcpf(x); }

// fast erf: Abramowitz-Stegun 7.1.26, |err| <= 1.5e-7 (rcp instead of IEEE div)
__device__ __forceinline__ float erf_fast(float x) {
    float ax = fabsf(x);
    float t = rcp_(fmaf(0.3275911f, ax, 1.0f));
    float y = t * fmaf(t, fmaf(t, fmaf(t, fmaf(t, 1.061405429f, -1.453152027f),
                                       1.421413741f), -0.284496736f), 0.254829592f);
    float r = 1.0f - y * __expf(-ax * ax);
    return (x < 0.f) ? -r : r;
}
__device__ __forceinline__ float gelu_(float x) {
    return 0.5f * x * (1.0f + erf_fast(x * 0.70710678118654752f));
}
__device__ __forceinline__ float silu_(float x) {
    return x * rcp_(1.0f + __expf(-x));
}

// batched float2 block reduction over 256 threads (4 waves)
__device__ __forceinline__ float2 block_reduce256_f2(float2 v, float2* red) {
    #pragma unroll
    for (int o = 32; o > 0; o >>= 1) {
        v.x += __shfl_xor(v.x, o); v.y += __shfl_xor(v.y, o);
    }
    __syncthreads();
    if ((threadIdx.x & 63) == 0) red[threadIdx.x >> 6] = v;
    __syncthreads();
    float2 r = red[0];
    #pragma unroll
    for (int w2 = 1; w2 < 4; w2++) {
        float2 o = red[w2];
        r.x += o.x; r.y += o.y;
    }
    return r;
}

// dual float4 block reduction over 384 threads (6 waves): one barrier for 8 values.
__device__ __forceinline__ void block_reduce8(float4& va, float4& vb, bool ismax,
                                              float4* red, int base) {
    #pragma unroll
    for (int o = 32; o > 0; o >>= 1) {
        float ax = __shfl_xor(va.x, o), ay = __shfl_xor(va.y, o);
        float az = __shfl_xor(va.z, o), aw = __shfl_xor(va.w, o);
        float bx = __shfl_xor(vb.x, o), by = __shfl_xor(vb.y, o);
        float bz = __shfl_xor(vb.z, o), bw = __shfl_xor(vb.w, o);
        if (ismax) {
            va.x = fmaxf(va.x, ax); va.y = fmaxf(va.y, ay); va.z = fmaxf(va.z, az); va.w = fmaxf(va.w, aw);
            vb.x = fmaxf(vb.x, bx); vb.y = fmaxf(vb.y, by); vb.z = fmaxf(vb.z, bz); vb.w = fmaxf(vb.w, bw);
        } else {
            va.x += ax; va.y += ay; va.z += az; va.w += aw;
            vb.x += bx; vb.y += by; vb.z += bz; vb.w += bw;
        }
    }
    if ((threadIdx.x & 63) == 0) {
        red[base * 8 + (threadIdx.x >> 6)]       = va;
        red[(base + 1) * 8 + (threadIdx.x >> 6)] = vb;
    }
    __syncthreads();
    va = red[base * 8]; vb = red[(base + 1) * 8];
    #pragma unroll
    for (int w2 = 1; w2 < 6; w2++) {
        float4 oa = red[base * 8 + w2], ob = red[(base + 1) * 8 + w2];
        if (ismax) {
            va.x = fmaxf(va.x, oa.x); va.y = fmaxf(va.y, oa.y); va.z = fmaxf(va.z, oa.z); va.w = fmaxf(va.w, oa.w);
            vb.x = fmaxf(vb.x, ob.x); vb.y = fmaxf(vb.y, ob.y); vb.z = fmaxf(vb.z, ob.z); vb.w = fmaxf(vb.w, ob.w);
        } else {
            va.x += oa.x; va.y += oa.y; va.z += oa.z; va.w += oa.w;
            vb.x += ob.x; vb.y += ob.y; vb.z += ob.z; vb.w += ob.w;
        }
    }
}

// ---------- K1: LayerNorm + QKV (2 rows/block -> 384 blocks, f16 q/k out) + gates ----------
__global__ __launch_bounds__(256) void eq_k1(
    const float* __restrict__ feats, const float* __restrict__ gamma,
    const float* __restrict__ w_qkv, const float* __restrict__ w_gate,
    const float* __restrict__ b_gate,
    _Float16* __restrict__ qh, _Float16* __restrict__ kh, float* __restrict__ v,
    float* __restrict__ og, float* __restrict__ rg) {
    const int r0 = blockIdx.x * 2;
    const int b = r0 / N_;
    const int t = threadIdx.x;
    __shared__ float xs[2][DIM_];
    __shared__ float2 red2k[4];
    __shared__ float gredS[16][17];
    float2 f;
    f.x = feats[(long)(r0 + 0) * DIM_ + t];
    f.y = feats[(long)(r0 + 1) * DIM_ + t];
    float2 s = block_reduce256_f2(f, red2k);
    float mx = s.x * (1.f/DIM_), my = s.y * (1.f/DIM_);
    float2 d = make_float2(f.x - mx, f.y - my);
    float2 vr = block_reduce256_f2(make_float2(d.x*d.x, d.y*d.y), red2k);
    float g = gamma[t];
    xs[0][t] = d.x * rsqrtf(vr.x * (1.f/DIM_) + 1e-5f) * g;
    xs[1][t] = d.y * rsqrtf(vr.y * (1.f/DIM_) + 1e-5f) * g;
    __syncthreads();
    float acc[6];
    #pragma unroll
    for (int k = 0; k < 6; k++) acc[k] = 0.f;
    for (int c = 0; c < DIM_; c++) {
        const float* wr = w_qkv + (long)c * 768;
        float w0 = wr[t], w1 = wr[t + 256], w2 = wr[t + 512];
        #pragma unroll
        for (int r = 0; r < 2; r++) {
            float xc = xs[r][c];
            acc[r * 3 + 0] += xc * w0;
            acc[r * 3 + 1] += xc * w1;
            acc[r * 3 + 2] += xc * w2;
        }
    }
    int h = t >> 6, dd = t & 63;
    #pragma unroll
    for (int r = 0; r < 2; r++) {
        int n = r0 + r - b * N_;
        long idx = ((long)(b * H_ + h) * N_ + n) * DH_ + dd;
        qh[idx] = (_Float16)(acc[r * 3 + 0] * 0.125f);     // dh^-0.5 pre-applied
        kh[idx] = (_Float16)(acc[r * 3 + 1]);
        v[idx]  = acc[r * 3 + 2];
    }
    // ---- gates: all 256 threads, 16 outputs x 16 chunks of 16 channels ----
    {
        const int o = t & 15, chunk = t >> 4;       // o: gg = o&7, rr = o>>3
        const int gg = o & 7, rr = o >> 3;
        float part = 0.f;
        #pragma unroll
        for (int k = 0; k < 16; k++) {
            int c = chunk * 16 + k;
            part += xs[rr][c] * w_gate[c * 8 + gg];
        }
        gredS[chunk][o] = part;
    }
    __syncthreads();
    if (t < 16) {
        float a = b_gate[t & 7];
        #pragma unroll
        for (int k = 0; k < 16; k++) a += gredS[k][t];
        float gv = rcp_(1.0f + __expf(-a));
        int rr2 = t >> 3, g2 = t & 7;
        int n = r0 + rr2 - b * N_;
        if (g2 < 4) og[(b * H_ + g2) * N_ + n] = gv;
        else        rg[(b * H_ + (g2 - 4)) * N_ + n] = gv;
    }
}

// ---------- K2: position-bias MLP (MFMA), SYMMETRY-HALVED tile jobs ----------
// 512 threads, waves_per_eu(2,2) — measured-good round-7 config (75.9us).
// LDS: 16 slices (one per tile row) -> 145152 B total. ROUND-14 BUG: was
// launched with 110336 B (8-slice size from pre-symmetry kernel); slices
// rows 8-15 overflowed the dynamic-LDS allocation -> absmax 5.6e-2.
// A2d hoist: layer0 for BOTH row-units precomputed so silu chains overlap.
#define MFMA16(a, b, c) __builtin_amdgcn_mfma_f32_16x16x32_f16(a, b, c, 0, 0, 0)

#define LNAPPLY(gr_, ber_)                                                        \
{                                                                                  \
    _Pragma("unroll")                                                              \
    for (int rg2 = 0; rg2 < 4; rg2++) {                                            \
        float s = 0.f, sq = 0.f;                                                   \
        _Pragma("unroll")                                                          \
        for (int nt = 0; nt < 8; nt++) {                                           \
            float v0 = acc[nt][rg2]; s += v0; sq += v0 * v0;                       \
        }                                                                          \
        s += __shfl_xor(s, 1); sq += __shfl_xor(sq, 1);                            \
        s += __shfl_xor(s, 2); sq += __shfl_xor(sq, 2);                            \
        s += __shfl_xor(s, 4); sq += __shfl_xor(sq, 4);                            \
        s += __shfl_xor(s, 8); sq += __shfl_xor(sq, 8);                            \
        float mean = s * (1.f / 128.f);                                            \
        float inv = rsqrtf(sq * (1.f / 128.f) - mean * mean + 1e-5f);              \
        int row2 = quad * 4 + rg2;                                                 \
        _Pragma("unroll")                                                          \
        for (int nt = 0; nt < 8; nt++) {                                           \
            float y = (acc[nt][rg2] - mean) * inv * gr_[nt] + ber_[nt];            \
            myslice[row2 * 136 + nt * 16 + l15] = (_Float16)silu_(y);              \
        }                                                                          \
    }                                                                              \
}

__global__ __launch_bounds__(512) __attribute__((amdgpu_waves_per_eu(2, 2)))
void eq_k2(
    const float* __restrict__ coors,
    const float* __restrict__ w0, const float* __restrict__ b0,
    const float* __restrict__ g0, const float* __restrict__ be0,
    const float* __restrict__ W1g, const float* __restrict__ b1,
    const float* __restrict__ g1, const float* __restrict__ be1,
    const float* __restrict__ W2g, const float* __restrict__ b2,
    const float* __restrict__ g2, const float* __restrict__ be2,
    const float* __restrict__ wqk, const float* __restrict__ bqk,
    const _Float16* __restrict__ qh, const _Float16* __restrict__ kh,
    _Float16* __restrict__ pT, float* __restrict__ qkpos,
    float* __restrict__ qkq) {

    extern __shared__ char smem[];
    _Float16* W1T    = (_Float16*)smem;                   // 128x136 = 34816 B
    _Float16* W2T    = (_Float16*)(smem + 34816);         // 34816 B
    _Float16* wqT    = (_Float16*)(smem + 69632);         // 16x136 = 4352 B
    float*    PQR    = (float*)(smem + 73984);            // 1536 B
    _Float16* slices = (_Float16*)(smem + 75520);         // 16 x 16x136 = 69632 B
    // total 145152 B -> 1 block/CU (8 waves, 2/SIMD)

    const int t = threadIdx.x;
    const int lane = t & 63, wv = t >> 6;
    const int l15 = lane & 15, quad = lane >> 4;

    for (int idx = t; idx < 16384; idx += 512) {
        int k = idx >> 7, n = idx & 127;
        W1T[n * 136 + k] = (_Float16)W1g[idx];
        W2T[n * 136 + k] = (_Float16)W2g[idx];
    }
    for (int idx = t; idx < 2048; idx += 512) {
        int n = idx >> 7, k = idx & 127;
        wqT[n * 136 + k] = (n < 4) ? (_Float16)wqk[k * 4 + n] : (_Float16)0.f;
    }
    float Sw = 0, Sb = 0, Sww = 0, Swb = 0, Sbb = 0;
    for (int c = 0; c < 128; c++) {
        float w = w0[c], bb2v = b0[c];
        Sw += w; Sb += bb2v; Sww += w * w; Swb += w * bb2v; Sbb += bb2v * bb2v;
    }
    const float mw = Sw * (1.f / 128.f), mbb = Sb * (1.f / 128.f);
    const float A2 = Sww * (1.f / 128.f) - mw * mw;
    const float AD = Swb * (1.f / 128.f) - mw * mbb;
    const float D2 = Sbb * (1.f / 128.f) - mbb * mbb;
    if (t < 128) {
        PQR[t]       = (w0[t] - mw) * g0[t];
        PQR[128 + t] = (b0[t] - mbb) * g0[t];
        PQR[256 + t] = be0[t];
    }
    // loop-invariant per-lane channel params in registers (c = nt*16 + l15)
    float b1r[8], b2r[8], g1r[8], be1r[8], g2r[8], be2r[8];
    #pragma unroll
    for (int nt = 0; nt < 8; nt++) {
        int c = nt * 16 + l15;
        b1r[nt] = b1[c]; b2r[nt] = b2[c];
        g1r[nt] = g1[c]; be1r[nt] = be1[c];
        g2r[nt] = g2[c]; be2r[nt] = be2[c];
    }
    const float bqv = (l15 < 4) ? bqk[l15] : 0.f;
    __syncthreads();

    for (int jo = blockIdx.x; jo < JOBS_; jo += 256) {
        // unrank job -> (b, it, jt) with it <= jt
        int b = jo / TPB_;
        int tt2 = jo - b * TPB_;
        int it = 0, rl = NT_;
        while (tt2 >= rl) { tt2 -= rl; it++; rl--; }
        const int jt = it + tt2;
        const int j0 = jt * 16;

        // ---- layer0 for BOTH row-units up front: the two silu chains
        //      overlap each other and the downstream MFMA pipeline ----
        v8h A2d[2][4];
        #pragma unroll
        for (int rr = 0; rr < 2; rr++) {
            const int ii = it * 16 + wv + rr * 8;
            const float cix = coors[(b * N_ + ii) * 3 + 0];
            const float ciy = coors[(b * N_ + ii) * 3 + 1];
            const float ciz = coors[(b * N_ + ii) * 3 + 2];
            float tt, uu;
            {
                int j = j0 + l15;
                float dx = cix - coors[(b * N_ + j) * 3 + 0];
                float dy = ciy - coors[(b * N_ + j) * 3 + 1];
                float dz = ciz - coors[(b * N_ + j) * 3 + 2];
                float d = sqrtf(dx * dx + dy * dy + dz * dz);
                float var = (d * d) * A2 + 2.f * d * AD + D2;
                float inv = rsqrtf(var + 1e-5f);
                tt = d * inv; uu = inv;
            }
            #pragma unroll
            for (int kt = 0; kt < 4; kt++) {
                int base = kt * 32 + quad * 8;
                float4 Pa = *(const float4*)&PQR[base],       Pb = *(const float4*)&PQR[base + 4];
                float4 Qa = *(const float4*)&PQR[128 + base], Qb = *(const float4*)&PQR[128 + base + 4];
                float4 Ra = *(const float4*)&PQR[256 + base], Rb = *(const float4*)&PQR[256 + base + 4];
                float Pj[8] = {Pa.x, Pa.y, Pa.z, Pa.w, Pb.x, Pb.y, Pb.z, Pb.w};
                float Qj[8] = {Qa.x, Qa.y, Qa.z, Qa.w, Qb.x, Qb.y, Qb.z, Qb.w};
                float Rj[8] = {Ra.x, Ra.y, Ra.z, Ra.w, Rb.x, Rb.y, Rb.z, Rb.w};
                v8h av;
                #pragma unroll
                for (int jj = 0; jj < 8; jj++) {
                    float y = tt * Pj[jj] + uu * Qj[jj] + Rj[jj];
                    av[jj] = (_Float16)silu_(y);
                }
                A2d[rr][kt] = av;
            }
        }

        #pragma unroll 1
        for (int rr = 0; rr < 2; rr++) {
            const int r = wv + rr * 8;            // row-within-tile 0..15
            const int ii = it * 16 + r;
            _Float16* myslice = slices + r * 2176;
            v8h A[4];
            #pragma unroll
            for (int kt = 0; kt < 4; kt++) A[kt] = A2d[rr][kt];

            v4f acc[8];
            #pragma unroll
            for (int nt = 0; nt < 8; nt++) {
                v4f ci = {b1r[nt], b1r[nt], b1r[nt], b1r[nt]};
                acc[nt] = ci;
            }
            #pragma unroll
            for (int kt = 0; kt < 4; kt++) {
                #pragma unroll
                for (int nt = 0; nt < 8; nt++) {
                    v8h Bv = *(const v8h*)&W1T[(nt * 16 + l15) * 136 + kt * 32 + quad * 8];
                    acc[nt] = MFMA16(A[kt], Bv, acc[nt]);
                }
            }
            LNAPPLY(g1r, be1r)
            #pragma unroll
            for (int kt = 0; kt < 4; kt++)
                A[kt] = *(const v8h*)&myslice[l15 * 136 + kt * 32 + quad * 8];
            #pragma unroll
            for (int nt = 0; nt < 8; nt++) {
                v4f ci = {b2r[nt], b2r[nt], b2r[nt], b2r[nt]};
                acc[nt] = ci;
            }
            #pragma unroll
            for (int kt = 0; kt < 4; kt++) {
                #pragma unroll
                for (int nt = 0; nt < 8; nt++) {
                    v8h Bv = *(const v8h*)&W2T[(nt * 16 + l15) * 136 + kt * 32 + quad * 8];
                    acc[nt] = MFMA16(A[kt], Bv, acc[nt]);
                }
            }
            LNAPPLY(g2r, be2r)
            // ---- qk_pos = p @ wqk + bqk (direct + mirror) ----
            {
                v4f c = {0.f, 0.f, 0.f, 0.f};
                #pragma unroll
                for (int kt = 0; kt < 4; kt++) {
                    v8h av = *(const v8h*)&myslice[l15 * 136 + kt * 32 + quad * 8];
                    v8h wq = *(const v8h*)&wqT[l15 * 136 + kt * 32 + quad * 8];
                    c = MFMA16(av, wq, c);
                }
                if (l15 < 4) {
                    #pragma unroll
                    for (int rg2 = 0; rg2 < 4; rg2++) {
                        int rowj = quad * 4 + rg2;
                        float val = c[rg2] + bqv;
                        qkpos[((long)(b * N_ + ii) * N_ + j0 + rowj) * 4 + l15] = val;
                        if (it != jt)
                            qkpos[((long)(b * N_ + j0 + rowj) * N_ + ii) * 4 + l15] = val;
                    }
                }
            }
        }
        __syncthreads();   // all 16 slices of this tile complete

        // ---- cooperative chunk writes: wave wv -> rows {2wv, 2wv+1} ----
        #pragma unroll
        for (int rx = 0; rx < 2; rx++) {
            const int r2 = wv * 2 + rx;
            // direct chunk: consumer row (b, it*16+r2), j-tile jt: [c][j16]
            {
                const _Float16* src = slices + r2 * 2176;
                _Float16* chunk = pT + (((long)(b * N_ + it * 16 + r2) * 24 + jt) << 11);
                #pragma unroll
                for (int cc = 0; cc < 2; cc++) {
                    int c = lane + cc * 64;
                    v8h lo, hi;
                    #pragma unroll
                    for (int k = 0; k < 8; k++) {
                        lo[k] = src[k * 136 + c];
                        hi[k] = src[(k + 8) * 136 + c];
                    }
                    *(v8h*)(chunk + c * 16)     = lo;
                    *(v8h*)(chunk + c * 16 + 8) = hi;
                }
            }
            // mirror chunk: consumer row (b, jt*16+r2), j-tile it: [c][i16]
            if (it != jt) {
                _Float16* chunk = pT + (((long)(b * N_ + jt * 16 + r2) * 24 + it) << 11);
                #pragma unroll
                for (int cc = 0; cc < 2; cc++) {
                    int c = lane + cc * 64;
                    v8h lo, hi;
                    #pragma unroll
                    for (int r = 0; r < 8; r++) {
                        lo[r] = slices[r * 2176 + r2 * 136 + c];
                        hi[r] = slices[(r + 8) * 2176 + r2 * 136 + c];
                    }
                    *(v8h*)(chunk + c * 16)     = lo;
                    *(v8h*)(chunk + c * 16 + 8) = hi;
                }
            }
        }
        __syncthreads();   // protect slices before next job
    }

    // ---- fused former K2b: blocks 88..135 (2-job blocks) do qk tiles ----
    {
        int gw = (blockIdx.x - 88) * 8 + wv;
        if (blockIdx.x >= 88 && gw < 384) {
            const int bh = gw / 48;
            const int rest = gw - bh * 48;
            const int it = rest >> 1, nh = rest & 1;
            const int bb = bh >> 2, hh = bh & 3;
            const int i0 = it * 16;
            v8h A0 = *(const v8h*)&qh[((long)(bh * N_) + i0 + l15) * DH_ + quad * 8];
            v8h A1 = *(const v8h*)&qh[((long)(bh * N_) + i0 + l15) * DH_ + 32 + quad * 8];
            #pragma unroll 1
            for (int nt = 0; nt < 12; nt++) {
                int jq0 = nh * 192 + nt * 16;
                v8h B0 = *(const v8h*)&kh[((long)(bh * N_) + jq0 + l15) * DH_ + quad * 8];
                v8h B1 = *(const v8h*)&kh[((long)(bh * N_) + jq0 + l15) * DH_ + 32 + quad * 8];
                v4f c = {0.f, 0.f, 0.f, 0.f};
                c = MFMA16(A0, B0, c);
                c = MFMA16(A1, B1, c);
                #pragma unroll
                for (int rg2 = 0; rg2 < 4; rg2++) {
                    int i = i0 + quad * 4 + rg2;
                    int j = jq0 + l15;
                    long idx = (((long)(bb * N_ + i)) * N_ + j) * 4 + hh;
                    qkq[idx] = c[rg2];
                }
            }
        }
    }
}

// ---------- K3A: per-pair edge-MLP (no barriers, streaming). cmi overwrites qkq in-place ----------
__global__ __launch_bounds__(256) void eq_k3a(
    const float* __restrict__ edges, const float* __restrict__ qkpos,
    float* __restrict__ qkq,
    const float* __restrict__ w_e1, const float* __restrict__ w_e2) {
    __shared__ _Float16 we1h[20 * 40];
    __shared__ float we2[40 * 4];
    const int t = threadIdx.x;
    for (int idx = t; idx < 800; idx += 256) we1h[idx] = (_Float16)w_e1[idx];
    if (t < 160) we2[t] = w_e2[t];
    __syncthreads();

    const long pair = (long)blockIdx.x * 256 + t;   // 294912 pairs = 1152 blocks
    float in20[20];
    {
        float4 qp = *(const float4*)(qkpos + pair * 4);
        float4 qq = *(const float4*)(qkq + pair * 4);
        in20[0] = qp.x + qq.x; in20[1] = qp.y + qq.y;
        in20[2] = qp.z + qq.z; in20[3] = qp.w + qq.w;
    }
    const float4* ep = (const float4*)(edges + pair * ED_);
    float4 e0 = ep[0], e1 = ep[1], e2 = ep[2], e3 = ep[3];
    in20[4] = e0.x;  in20[5] = e0.y;  in20[6] = e0.z;  in20[7] = e0.w;
    in20[8] = e1.x;  in20[9] = e1.y;  in20[10] = e1.z; in20[11] = e1.w;
    in20[12] = e2.x; in20[13] = e2.y; in20[14] = e2.z; in20[15] = e2.w;
    in20[16] = e3.x; in20[17] = e3.y; in20[18] = e3.z; in20[19] = e3.w;

    float c0 = 0, c1 = 0, c2 = 0, c3 = 0;
    #pragma unroll 1
    for (int oc = 0; oc < 5; oc++) {
        float a8[8] = {0.f, 0.f, 0.f, 0.f, 0.f, 0.f, 0.f, 0.f};
        #pragma unroll
        for (int c = 0; c < 20; c++) {
            float xc = in20[c];
            v8h wv = *(const v8h*)&we1h[c * 40 + oc * 8];   // 16B aligned: 80c + 16*oc
            #pragma unroll
            for (int o2 = 0; o2 < 8; o2++) a8[o2] += xc * (float)wv[o2];
        }
        #pragma unroll
        for (int o = 0; o < 8; o++) {
            float gg = gelu_(a8[o]);
            float4 w2v = *(const float4*)&we2[(oc * 8 + o) * 4];
            c0 += gg * w2v.x; c1 += gg * w2v.y; c2 += gg * w2v.z; c3 += gg * w2v.w;
        }
    }
    *(float4*)(qkq + pair * 4) = make_float4(c0, c1, c2, c3);
}

// ---------- K3B: softmax/coor-branch/ap(MFMA)/attn@v/out-proj (reads cmi) ----------
__global__ __launch_bounds__(384) void eq_k3b(
    const float* __restrict__ cmig,
    const _Float16* __restrict__ pT, const float* __restrict__ v,
    const float* __restrict__ coors,
    const float* __restrict__ w_c, const float* __restrict__ w_cg,
    const float* __restrict__ b_cg, const float* __restrict__ w_th,
    const float* __restrict__ cscale, const float* __restrict__ ccomb,
    const float* __restrict__ og, const float* __restrict__ rg,
    const float* __restrict__ w_vpos, const float* __restrict__ b_vpos,
    const float* __restrict__ w_out, const float* __restrict__ b_out,
    float* __restrict__ out0, float* __restrict__ out1) {
    int row = blockIdx.x;           // b*N + i
    int b = row / N_, i = row - b * N_;
    int j = threadIdx.x;            // 0..383
    __shared__ float wcs[16], wcgs[16], bcgs[4], wths[16];
    __shared__ float attnS[4 * N_];
    __shared__ float apS[2 * 4 * PD_];
    __shared__ float nodeS[256];
    __shared__ float4 red4[50];     // [0..31] reduce8 slots (base 0..3), [32..49] reduce12

    if (j < 16) { wcs[j] = w_c[j]; wcgs[j] = w_cg[j]; wths[j] = w_th[j]; }
    if (j < 4) bcgs[j] = b_cg[j];
    __syncthreads();

    // ---- cmi from K3A; derive gc/cp/rs ----
    long pair = ((long)row) * N_ + j;
    float4 cm = *(const float4*)(cmig + pair * 4);
    float cmi[4] = {cm.x, cm.y, cm.z, cm.w};
    float gc[4], cp[4], rs[4];
    #pragma unroll
    for (int h = 0; h < 4; h++) gc[h] = gelu_(cmi[h]);
    #pragma unroll
    for (int h = 0; h < 4; h++) {
        cp[h] = gc[0] * wcs[h] + gc[1] * wcs[4 + h] + gc[2] * wcs[8 + h] + gc[3] * wcs[12 + h];
        rs[h] = cmi[0] * wcgs[h] + cmi[1] * wcgs[4 + h] + cmi[2] * wcgs[8 + h] + cmi[3] * wcgs[12 + h] + bcgs[h];
    }

    // ---- fused reductions (2 barriers) + coordinate geometry ----
    float dx = coors[(b * N_ + i) * 3 + 0] - coors[(b * N_ + j) * 3 + 0];
    float dy = coors[(b * N_ + i) * 3 + 1] - coors[(b * N_ + j) * 3 + 1];
    float dz = coors[(b * N_ + i) * 3 + 2] - coors[(b * N_ + j) * 3 + 2];
    float nrm = sqrtf(dx * dx + dy * dy + dz * dz);
    float sc = cscale[0] * rcp_(fmaxf(nrm, 1e-8f));
    float rx = dx * sc, ry = dy * sc, rz = dz * sc;

    float4 m4  = make_float4(cmi[0], cmi[1], cmi[2], cmi[3]);
    float4 cm4 = make_float4(cp[0], cp[1], cp[2], cp[3]);
    block_reduce8(m4, cm4, true, red4, 0);
    float e[4], ec[4];
    e[0] = __expf(cmi[0] - m4.x); e[1] = __expf(cmi[1] - m4.y);
    e[2] = __expf(cmi[2] - m4.z); e[3] = __expf(cmi[3] - m4.w);
    ec[0] = __expf(cp[0] - cm4.x); ec[1] = __expf(cp[1] - cm4.y);
    ec[2] = __expf(cp[2] - cm4.z); ec[3] = __expf(cp[3] - cm4.w);
    float4 l4  = make_float4(e[0], e[1], e[2], e[3]);
    float4 cl4 = make_float4(ec[0], ec[1], ec[2], ec[3]);
    block_reduce8(l4, cl4, false, red4, 2);

    float sm[4] = {e[0] * rcp_(l4.x), e[1] * rcp_(l4.y), e[2] * rcp_(l4.z), e[3] * rcp_(l4.w)};
    #pragma unroll
    for (int h = 0; h < 4; h++)
        attnS[h * N_ + j] = wths[h * 4 + 0] * sm[0] + wths[h * 4 + 1] * sm[1]
                          + wths[h * 4 + 2] * sm[2] + wths[h * 4 + 3] * sm[3];

    float w[4] = {ec[0] * rcp_(cl4.x) * rs[0], ec[1] * rcp_(cl4.y) * rs[1],
                  ec[2] * rcp_(cl4.z) * rs[2], ec[3] * rcp_(cl4.w) * rs[3]};
    float rv[12];
    #pragma unroll
    for (int h = 0; h < 4; h++) { rv[h] = w[h] * rx; rv[4 + h] = w[h] * ry; rv[8 + h] = w[h] * rz; }
    #pragma unroll
    for (int o = 32; o > 0; o >>= 1) {
        #pragma unroll
        for (int k = 0; k < 12; k++) rv[k] += __shfl_xor(rv[k], o);
    }
    if ((j & 63) == 0) {
        int wid = j >> 6;
        red4[32 + wid * 3 + 0] = make_float4(rv[0], rv[1], rv[2], rv[3]);
        red4[32 + wid * 3 + 1] = make_float4(rv[4], rv[5], rv[6], rv[7]);
        red4[32 + wid * 3 + 2] = make_float4(rv[8], rv[9], rv[10], rv[11]);
    }
    __syncthreads();    // attnS + reduce12 ready
    if (j == 0) {
        float4 sx4 = red4[32], sy4 = red4[33], sz4 = red4[34];
        #pragma unroll
        for (int w2 = 1; w2 < 6; w2++) {
            float4 ax = red4[32 + w2 * 3 + 0], ay = red4[32 + w2 * 3 + 1], az = red4[32 + w2 * 3 + 2];
            sx4.x += ax.x; sx4.y += ax.y; sx4.z += ax.z; sx4.w += ax.w;
            sy4.x += ay.x; sy4.y += ay.y; sy4.z += ay.z; sy4.w += ay.w;
            sz4.x += az.x; sz4.y += az.y; sz4.z += az.z; sz4.w += az.w;
        }
        float f0 = ccomb[0] * rg[(b * H_ + 0) * N_ + i];
        float f1 = ccomb[1] * rg[(b * H_ + 1) * N_ + i];
        float f2 = ccomb[2] * rg[(b * H_ + 2) * N_ + i];
        float f3 = ccomb[3] * rg[(b * H_ + 3) * N_ + i];
        out1[(b * N_ + i) * 3 + 0] = f0 * sx4.x + f1 * sx4.y + f2 * sx4.z + f3 * sx4.w;
        out1[(b * N_ + i) * 3 + 1] = f0 * sy4.x + f1 * sy4.y + f2 * sy4.z + f3 * sy4.w;
        out1[(b * N_ + i) * 3 + 2] = f0 * sz4.x + f1 * sz4.y + f2 * sz4.z + f3 * sz4.w;
    }

    // ---- phase D: waves 0-1 -> ap via MFMA; threads 128..383 -> attn@v ----
    if (j < 128) {
        const int lane = j & 63, l15d = lane & 15, quadd = lane >> 4;
        const int parity = j >> 6;
        const int hh = l15d & 3;
        const float msk = (l15d < 4) ? 1.f : 0.f;
        v4f acc[8];
        #pragma unroll
        for (int nt = 0; nt < 8; nt++) { v4f z = {0.f, 0.f, 0.f, 0.f}; acc[nt] = z; }
        #pragma unroll 2
        for (int kth = 0; kth < 6; kth++) {
            int kt = parity * 6 + kth;
            float4 a0 = *(const float4*)&attnS[hh * N_ + kt * 32 + quadd * 8];
            float4 a1 = *(const float4*)&attnS[hh * N_ + kt * 32 + quadd * 8 + 4];
            v8h Af;
            Af[0] = (_Float16)(a0.x * msk); Af[1] = (_Float16)(a0.y * msk);
            Af[2] = (_Float16)(a0.z * msk); Af[3] = (_Float16)(a0.w * msk);
            Af[4] = (_Float16)(a1.x * msk); Af[5] = (_Float16)(a1.y * msk);
            Af[6] = (_Float16)(a1.z * msk); Af[7] = (_Float16)(a1.w * msk);
            const _Float16* chunkp = pT + (((long)row * 24 + kt * 2 + (quadd >> 1)) << 11)
                                        + ((quadd & 1) << 3);
            #pragma unroll
            for (int nt = 0; nt < 8; nt++) {
                v8h Bv = *(const v8h*)&chunkp[(nt * 16 + l15d) * 16];
                acc[nt] = MFMA16(Af, Bv, acc[nt]);
            }
        }
        if (quadd == 0) {
            #pragma unroll
            for (int nt = 0; nt < 8; nt++)
                #pragma unroll
                for (int rg2 = 0; rg2 < 4; rg2++)
                    apS[parity * 512 + rg2 * 128 + nt * 16 + l15d] = acc[nt][rg2];
        }
    } else {
        int tt = j - 128, h = tt >> 6, d = tt & 63;
        float acc0 = 0, acc1 = 0, acc2 = 0, acc3 = 0;
        const float* vp = v + ((long)(b * H_ + h) * N_) * DH_ + d;
        #pragma unroll 8
        for (int jj = 0; jj < N_; jj += 4) {
            float4 a = *(const float4*)&attnS[h * N_ + jj];
            acc0 += a.x * vp[(long)(jj + 0) * DH_];
            acc1 += a.y * vp[(long)(jj + 1) * DH_];
            acc2 += a.z * vp[(long)(jj + 2) * DH_];
            acc3 += a.w * vp[(long)(jj + 3) * DH_];
        }
        nodeS[tt] = (acc0 + acc1) + (acc2 + acc3);
    }
    __syncthreads();

    // ---- phase E: node = (attnv + ap@w_vpos + Sh*b_vpos) * out_gate ----
    // thread j reads and writes only nodeS[j] -> no barrier needed between
    if (j < 256) {
        int h = j >> 6, d = j & 63;
        float accp = 0;
        const float* wv = w_vpos + h * DH_ + d;
        #pragma unroll 4
        for (int c4 = 0; c4 < 32; c4++) {
            float4 p0 = *(const float4*)&apS[h * 128 + c4 * 4];
            float4 p1 = *(const float4*)&apS[512 + h * 128 + c4 * 4];
            accp += (p0.x + p1.x) * wv[(long)(c4 * 4 + 0) * (H_ * DH_)]
                  + (p0.y + p1.y) * wv[(long)(c4 * 4 + 1) * (H_ * DH_)]
                  + (p0.z + p1.z) * wv[(long)(c4 * 4 + 2) * (H_ * DH_)]
                  + (p0.w + p1.w) * wv[(long)(c4 * 4 + 3) * (H_ * DH_)];
        }
        float Sh = wths[h * 4 + 0] + wths[h * 4 + 1] + wths[h * 4 + 2] + wths[h * 4 + 3];
        nodeS[j] = (nodeS[j] + accp + Sh * b_vpos[h * DH_ + d]) * og[(b * H_ + h) * N_ + i];
    }
    __syncthreads();

    // ---- phase F: out0 = node @ w_out + b_out ----
    if (j < 256) {
        float acc = b_out[j];
        const float* wo = w_out + j;
        #pragma unroll 4
        for (int c4 = 0; c4 < 64; c4++) {
            float4 nv4 = *(const float4*)&nodeS[c4 * 4];
            acc += nv4.x * wo[(long)(c4 * 4 + 0) * 256]
                 + nv4.y * wo[(long)(c4 * 4 + 1) * 256]
                 + nv4.z * wo[(long)(c4 * 4 + 2) * 256]
                 + nv4.w * wo[(long)(c4 * 4 + 3) * 256];
        }
        out0[(long)row * 256 + j] = acc;
    }
}

extern "C" void kernel_launch(void* const* d_in, const int* in_sizes, int n_in,
                              void* d_out, int out_size, void* d_ws, size_t ws_size,
                              hipStream_t stream) {
    (void)in_sizes; (void)n_in; (void)out_size; (void)ws_size;
    const float* feats   = (const float*)d_in[0];
    const float* coors   = (const float*)d_in[1];
    const float* edges   = (const float*)d_in[2];
    const float* gamma   = (const float*)d_in[3];
    const float* w_qkv   = (const float*)d_in[4];
    const float* w_gate  = (const float*)d_in[5];
    const float* b_gate  = (const float*)d_in[6];
    const float* w_th    = (const float*)d_in[7];
    const float* w_e1    = (const float*)d_in[8];
    const float* w_e2    = (const float*)d_in[9];
    const float* w_c     = (const float*)d_in[10];
    const float* w_cg    = (const float*)d_in[11];
    const float* b_cg    = (const float*)d_in[12];
    const float* cscale  = (const float*)d_in[13];
    const float* ccomb   = (const float*)d_in[14];
    const float* pb_w0   = (const float*)d_in[15];
    const float* pb_b0   = (const float*)d_in[16];
    const float* pb_g0   = (const float*)d_in[17];
    const float* pb_be0  = (const float*)d_in[18];
    const float* pb_w1   = (const float*)d_in[19];
    const float* pb_b1   = (const float*)d_in[20];
    const float* pb_g1   = (const float*)d_in[21];
    const float* pb_be1  = (const float*)d_in[22];
    const float* pb_w2   = (const float*)d_in[23];
    const float* pb_b2   = (const float*)d_in[24];
    const float* pb_g2   = (const float*)d_in[25];
    const float* pb_be2  = (const float*)d_in[26];
    const float* w_qkpos = (const float*)d_in[27];
    const float* b_qkpos = (const float*)d_in[28];
    const float* w_vpos  = (const float*)d_in[29];
    const float* b_vpos  = (const float*)d_in[30];
    const float* w_out   = (const float*)d_in[31];
    const float* b_out   = (const float*)d_in[32];

    // workspace carve (bytes)
    char* ws = (char*)d_ws;
    _Float16* qh   = (_Float16*)(ws + 0);            // 393216 B
    _Float16* kh   = (_Float16*)(ws + 393216);       // 393216 B
    float* v       = (float*)(ws + 786432);          // 786432 B
    float* og      = (float*)(ws + 1572864);         // 12288 B
    float* rg      = (float*)(ws + 1585152);         // 12288 B
    float* qkpos   = (float*)(ws + 1597440);         // 4718592 B
    _Float16* pT   = (_Float16*)(ws + 6316032);      // 75497472 B (tiled chunks)
    float* qkq     = (float*)(ws + 81813504);        // 4718592 B (qk dot, then cmi in-place)

    float* out0 = (float*)d_out;
    float* out1 = out0 + (long)B_ * N_ * DIM_;

    const int K2_LDS = 145152;    // 16 slices: 75520 + 69632 (round-14 fix: was 110336, OOB)
    hipFuncSetAttribute((const void*)eq_k2, hipFuncAttributeMaxDynamicSharedMemorySize, K2_LDS);

    eq_k1<<<384, 256, 0, stream>>>(feats, gamma, w_qkv, w_gate, b_gate, qh, kh, v, og, rg);
    eq_k2<<<256, 512, K2_LDS, stream>>>(coors, pb_w0, pb_b0, pb_g0, pb_be0,
                                        pb_w1, pb_b1, pb_g1, pb_be1,
                                        pb_w2, pb_b2, pb_g2, pb_be2,
                                        w_qkpos, b_qkpos, qh, kh, pT, qkpos, qkq);
    eq_k3a<<<(B_ * N_ * N_) / 256, 256, 0, stream>>>(edges, qkpos, qkq, w_e1, w_e2);
    eq_k3b<<<B_ * N_, 384, 0, stream>>>(qkq, pT, v, coors,
                                        w_c, w_cg, b_cg, w_th,
                                        cscale, ccomb, og, rg,
                                        w_vpos, b_vpos, w_out, b_out, out0, out1);
}

// Round 16
// 280.942 us; speedup vs baseline: 1.1533x; 1.1533x over previous
//
#include <hip/hip_runtime.h>
#include <hip/hip_bf16.h>

#define B_   2
#define N_   384
#define DIM_ 256
#define H_   4
#define DH_  64
#define PD_  128
#define ED_  16
#define NT_  24                 // j-tiles per row (N_/16)
#define TPB_ 300                // upper-tri tiles per batch: 24*25/2
#define JOBS_ 600               // total tile jobs (B_ * TPB_)

typedef _Float16 v8h __attribute__((ext_vector_type(8)));
typedef float    v4f __attribute__((ext_vector_type(4)));

__device__ __forceinline__ float rcp_(float x) { return __builtin_amdgcn_rcpf(x); }

// fast erf: Abramowitz-Stegun 7.1.26, |err| <= 1.5e-7 (rcp instead of IEEE div)
__device__ __forceinline__ float erf_fast(float x) {
    float ax = fabsf(x);
    float t = rcp_(fmaf(0.3275911f, ax, 1.0f));
    float y = t * fmaf(t, fmaf(t, fmaf(t, fmaf(t, 1.061405429f, -1.453152027f),
                                       1.421413741f), -0.284496736f), 0.254829592f);
    float r = 1.0f - y * __expf(-ax * ax);
    return (x < 0.f) ? -r : r;
}
__device__ __forceinline__ float gelu_(float x) {
    return 0.5f * x * (1.0f + erf_fast(x * 0.70710678118654752f));
}
__device__ __forceinline__ float silu_(float x) {
    return x * rcp_(1.0f + __expf(-x));
}

// batched float2 block reduction over 256 threads (4 waves)
__device__ __forceinline__ float2 block_reduce256_f2(float2 v, float2* red) {
    #pragma unroll
    for (int o = 32; o > 0; o >>= 1) {
        v.x += __shfl_xor(v.x, o); v.y += __shfl_xor(v.y, o);
    }
    __syncthreads();
    if ((threadIdx.x & 63) == 0) red[threadIdx.x >> 6] = v;
    __syncthreads();
    float2 r = red[0];
    #pragma unroll
    for (int w2 = 1; w2 < 4; w2++) {
        float2 o = red[w2];
        r.x += o.x; r.y += o.y;
    }
    return r;
}

// dual float4 block reduction over 384 threads (6 waves): one barrier for 8 values.
__device__ __forceinline__ void block_reduce8(float4& va, float4& vb, bool ismax,
                                              float4* red, int base) {
    #pragma unroll
    for (int o = 32; o > 0; o >>= 1) {
        float ax = __shfl_xor(va.x, o), ay = __shfl_xor(va.y, o);
        float az = __shfl_xor(va.z, o), aw = __shfl_xor(va.w, o);
        float bx = __shfl_xor(vb.x, o), by = __shfl_xor(vb.y, o);
        float bz = __shfl_xor(vb.z, o), bw = __shfl_xor(vb.w, o);
        if (ismax) {
            va.x = fmaxf(va.x, ax); va.y = fmaxf(va.y, ay); va.z = fmaxf(va.z, az); va.w = fmaxf(va.w, aw);
            vb.x = fmaxf(vb.x, bx); vb.y = fmaxf(vb.y, by); vb.z = fmaxf(vb.z, bz); vb.w = fmaxf(vb.w, bw);
        } else {
            va.x += ax; va.y += ay; va.z += az; va.w += aw;
            vb.x += bx; vb.y += by; vb.z += bz; vb.w += bw;
        }
    }
    if ((threadIdx.x & 63) == 0) {
        red[base * 8 + (threadIdx.x >> 6)]       = va;
        red[(base + 1) * 8 + (threadIdx.x >> 6)] = vb;
    }
    __syncthreads();
    va = red[base * 8]; vb = red[(base + 1) * 8];
    #pragma unroll
    for (int w2 = 1; w2 < 6; w2++) {
        float4 oa = red[base * 8 + w2], ob = red[(base + 1) * 8 + w2];
        if (ismax) {
            va.x = fmaxf(va.x, oa.x); va.y = fmaxf(va.y, oa.y); va.z = fmaxf(va.z, oa.z); va.w = fmaxf(va.w, oa.w);
            vb.x = fmaxf(vb.x, ob.x); vb.y = fmaxf(vb.y, ob.y); vb.z = fmaxf(vb.z, ob.z); vb.w = fmaxf(vb.w, ob.w);
        } else {
            va.x += oa.x; va.y += oa.y; va.z += oa.z; va.w += oa.w;
            vb.x += ob.x; vb.y += ob.y; vb.z += ob.z; vb.w += ob.w;
        }
    }
}

// ---------- K1: LayerNorm + QKV (2 rows/block -> 384 blocks, f16 q/k out) + gates ----------
__global__ __launch_bounds__(256) void eq_k1(
    const float* __restrict__ feats, const float* __restrict__ gamma,
    const float* __restrict__ w_qkv, const float* __restrict__ w_gate,
    const float* __restrict__ b_gate,
    _Float16* __restrict__ qh, _Float16* __restrict__ kh, float* __restrict__ v,
    float* __restrict__ og, float* __restrict__ rg) {
    const int r0 = blockIdx.x * 2;
    const int b = r0 / N_;
    const int t = threadIdx.x;
    __shared__ float xs[2][DIM_];
    __shared__ float2 red2k[4];
    __shared__ float gredS[16][17];
    float2 f;
    f.x = feats[(long)(r0 + 0) * DIM_ + t];
    f.y = feats[(long)(r0 + 1) * DIM_ + t];
    float2 s = block_reduce256_f2(f, red2k);
    float mx = s.x * (1.f/DIM_), my = s.y * (1.f/DIM_);
    float2 d = make_float2(f.x - mx, f.y - my);
    float2 vr = block_reduce256_f2(make_float2(d.x*d.x, d.y*d.y), red2k);
    float g = gamma[t];
    xs[0][t] = d.x * rsqrtf(vr.x * (1.f/DIM_) + 1e-5f) * g;
    xs[1][t] = d.y * rsqrtf(vr.y * (1.f/DIM_) + 1e-5f) * g;
    __syncthreads();
    float acc[6];
    #pragma unroll
    for (int k = 0; k < 6; k++) acc[k] = 0.f;
    for (int c = 0; c < DIM_; c++) {
        const float* wr = w_qkv + (long)c * 768;
        float w0 = wr[t], w1 = wr[t + 256], w2 = wr[t + 512];
        #pragma unroll
        for (int r = 0; r < 2; r++) {
            float xc = xs[r][c];
            acc[r * 3 + 0] += xc * w0;
            acc[r * 3 + 1] += xc * w1;
            acc[r * 3 + 2] += xc * w2;
        }
    }
    int h = t >> 6, dd = t & 63;
    #pragma unroll
    for (int r = 0; r < 2; r++) {
        int n = r0 + r - b * N_;
        long idx = ((long)(b * H_ + h) * N_ + n) * DH_ + dd;
        qh[idx] = (_Float16)(acc[r * 3 + 0] * 0.125f);     // dh^-0.5 pre-applied
        kh[idx] = (_Float16)(acc[r * 3 + 1]);
        v[idx]  = acc[r * 3 + 2];
    }
    // ---- gates: all 256 threads, 16 outputs x 16 chunks of 16 channels ----
    {
        const int o = t & 15, chunk = t >> 4;       // o: gg = o&7, rr = o>>3
        const int gg = o & 7, rr = o >> 3;
        float part = 0.f;
        #pragma unroll
        for (int k = 0; k < 16; k++) {
            int c = chunk * 16 + k;
            part += xs[rr][c] * w_gate[c * 8 + gg];
        }
        gredS[chunk][o] = part;
    }
    __syncthreads();
    if (t < 16) {
        float a = b_gate[t & 7];
        #pragma unroll
        for (int k = 0; k < 16; k++) a += gredS[k][t];
        float gv = rcp_(1.0f + __expf(-a));
        int rr2 = t >> 3, g2 = t & 7;
        int n = r0 + rr2 - b * N_;
        if (g2 < 4) og[(b * H_ + g2) * N_ + n] = gv;
        else        rg[(b * H_ + (g2 - 4)) * N_ + n] = gv;
    }
}

// ---------- K2: position-bias MLP (MFMA), SYMMETRY-HALVED tile jobs ----------
// Byte-exact round-7 measured-good version (75.9us): 512 threads,
// waves_per_eu(2,2), layer0 inside the per-rr loop. LDS 145152 B (16 slices).
// ROUND-15 LESSON: A2d hoist (+32 VGPR) crossed the 128-VGPR allocation
// cliff -> spills (FETCH 87MB, WRITE 218MB, 111us). This kernel sits ~4
// VGPRs under the cliff; register-adding edits need compile-check first.
#define MFMA16(a, b, c) __builtin_amdgcn_mfma_f32_16x16x32_f16(a, b, c, 0, 0, 0)

#define LNAPPLY(gr_, ber_)                                                        \
{                                                                                  \
    _Pragma("unroll")                                                              \
    for (int rg2 = 0; rg2 < 4; rg2++) {                                            \
        float s = 0.f, sq = 0.f;                                                   \
        _Pragma("unroll")                                                          \
        for (int nt = 0; nt < 8; nt++) {                                           \
            float v0 = acc[nt][rg2]; s += v0; sq += v0 * v0;                       \
        }                                                                          \
        s += __shfl_xor(s, 1); sq += __shfl_xor(sq, 1);                            \
        s += __shfl_xor(s, 2); sq += __shfl_xor(sq, 2);                            \
        s += __shfl_xor(s, 4); sq += __shfl_xor(sq, 4);                            \
        s += __shfl_xor(s, 8); sq += __shfl_xor(sq, 8);                            \
        float mean = s * (1.f / 128.f);                                            \
        float inv = rsqrtf(sq * (1.f / 128.f) - mean * mean + 1e-5f);              \
        int row2 = quad * 4 + rg2;                                                 \
        _Pragma("unroll")                                                          \
        for (int nt = 0; nt < 8; nt++) {                                           \
            float y = (acc[nt][rg2] - mean) * inv * gr_[nt] + ber_[nt];            \
            myslice[row2 * 136 + nt * 16 + l15] = (_Float16)silu_(y);              \
        }                                                                          \
    }                                                                              \
}

__global__ __launch_bounds__(512) __attribute__((amdgpu_waves_per_eu(2, 2)))
void eq_k2(
    const float* __restrict__ coors,
    const float* __restrict__ w0, const float* __restrict__ b0,
    const float* __restrict__ g0, const float* __restrict__ be0,
    const float* __restrict__ W1g, const float* __restrict__ b1,
    const float* __restrict__ g1, const float* __restrict__ be1,
    const float* __restrict__ W2g, const float* __restrict__ b2,
    const float* __restrict__ g2, const float* __restrict__ be2,
    const float* __restrict__ wqk, const float* __restrict__ bqk,
    const _Float16* __restrict__ qh, const _Float16* __restrict__ kh,
    _Float16* __restrict__ pT, float* __restrict__ qkpos,
    float* __restrict__ qkq) {

    extern __shared__ char smem[];
    _Float16* W1T    = (_Float16*)smem;                   // 128x136 = 34816 B
    _Float16* W2T    = (_Float16*)(smem + 34816);         // 34816 B
    _Float16* wqT    = (_Float16*)(smem + 69632);         // 16x136 = 4352 B
    float*    PQR    = (float*)(smem + 73984);            // 1536 B
    _Float16* slices = (_Float16*)(smem + 75520);         // 16 x 16x136 = 69632 B
    // total 145152 B -> 1 block/CU (8 waves, 2/SIMD)

    const int t = threadIdx.x;
    const int lane = t & 63, wv = t >> 6;
    const int l15 = lane & 15, quad = lane >> 4;

    for (int idx = t; idx < 16384; idx += 512) {
        int k = idx >> 7, n = idx & 127;
        W1T[n * 136 + k] = (_Float16)W1g[idx];
        W2T[n * 136 + k] = (_Float16)W2g[idx];
    }
    for (int idx = t; idx < 2048; idx += 512) {
        int n = idx >> 7, k = idx & 127;
        wqT[n * 136 + k] = (n < 4) ? (_Float16)wqk[k * 4 + n] : (_Float16)0.f;
    }
    float Sw = 0, Sb = 0, Sww = 0, Swb = 0, Sbb = 0;
    for (int c = 0; c < 128; c++) {
        float w = w0[c], bb2v = b0[c];
        Sw += w; Sb += bb2v; Sww += w * w; Swb += w * bb2v; Sbb += bb2v * bb2v;
    }
    const float mw = Sw * (1.f / 128.f), mbb = Sb * (1.f / 128.f);
    const float A2 = Sww * (1.f / 128.f) - mw * mw;
    const float AD = Swb * (1.f / 128.f) - mw * mbb;
    const float D2 = Sbb * (1.f / 128.f) - mbb * mbb;
    if (t < 128) {
        PQR[t]       = (w0[t] - mw) * g0[t];
        PQR[128 + t] = (b0[t] - mbb) * g0[t];
        PQR[256 + t] = be0[t];
    }
    // loop-invariant per-lane channel params in registers (c = nt*16 + l15)
    float b1r[8], b2r[8], g1r[8], be1r[8], g2r[8], be2r[8];
    #pragma unroll
    for (int nt = 0; nt < 8; nt++) {
        int c = nt * 16 + l15;
        b1r[nt] = b1[c]; b2r[nt] = b2[c];
        g1r[nt] = g1[c]; be1r[nt] = be1[c];
        g2r[nt] = g2[c]; be2r[nt] = be2[c];
    }
    const float bqv = (l15 < 4) ? bqk[l15] : 0.f;
    __syncthreads();

    for (int jo = blockIdx.x; jo < JOBS_; jo += 256) {
        // unrank job -> (b, it, jt) with it <= jt
        int b = jo / TPB_;
        int tt2 = jo - b * TPB_;
        int it = 0, rl = NT_;
        while (tt2 >= rl) { tt2 -= rl; it++; rl--; }
        const int jt = it + tt2;
        const int j0 = jt * 16;

        #pragma unroll 1
        for (int rr = 0; rr < 2; rr++) {
            const int r = wv + rr * 8;            // row-within-tile 0..15
            const int ii = it * 16 + r;
            _Float16* myslice = slices + r * 2176;
            const float cix = coors[(b * N_ + ii) * 3 + 0];
            const float ciy = coors[(b * N_ + ii) * 3 + 1];
            const float ciz = coors[(b * N_ + ii) * 3 + 2];
            float tt, uu;
            {
                int j = j0 + l15;
                float dx = cix - coors[(b * N_ + j) * 3 + 0];
                float dy = ciy - coors[(b * N_ + j) * 3 + 1];
                float dz = ciz - coors[(b * N_ + j) * 3 + 2];
                float d = sqrtf(dx * dx + dy * dy + dz * dz);
                float var = (d * d) * A2 + 2.f * d * AD + D2;
                float inv = rsqrtf(var + 1e-5f);
                tt = d * inv; uu = inv;
            }
            // layer0 directly into A-fragments (float4 PQR reads, rcp silu)
            v8h A[4];
            #pragma unroll
            for (int kt = 0; kt < 4; kt++) {
                int base = kt * 32 + quad * 8;
                float4 Pa = *(const float4*)&PQR[base],       Pb = *(const float4*)&PQR[base + 4];
                float4 Qa = *(const float4*)&PQR[128 + base], Qb = *(const float4*)&PQR[128 + base + 4];
                float4 Ra = *(const float4*)&PQR[256 + base], Rb = *(const float4*)&PQR[256 + base + 4];
                float Pj[8] = {Pa.x, Pa.y, Pa.z, Pa.w, Pb.x, Pb.y, Pb.z, Pb.w};
                float Qj[8] = {Qa.x, Qa.y, Qa.z, Qa.w, Qb.x, Qb.y, Qb.z, Qb.w};
                float Rj[8] = {Ra.x, Ra.y, Ra.z, Ra.w, Rb.x, Rb.y, Rb.z, Rb.w};
                v8h av;
                #pragma unroll
                for (int jj = 0; jj < 8; jj++) {
                    float y = tt * Pj[jj] + uu * Qj[jj] + Rj[jj];
                    av[jj] = (_Float16)silu_(y);
                }
                A[kt] = av;
            }
            v4f acc[8];
            #pragma unroll
            for (int nt = 0; nt < 8; nt++) {
                v4f ci = {b1r[nt], b1r[nt], b1r[nt], b1r[nt]};
                acc[nt] = ci;
            }
            #pragma unroll
            for (int kt = 0; kt < 4; kt++) {
                #pragma unroll
                for (int nt = 0; nt < 8; nt++) {
                    v8h Bv = *(const v8h*)&W1T[(nt * 16 + l15) * 136 + kt * 32 + quad * 8];
                    acc[nt] = MFMA16(A[kt], Bv, acc[nt]);
                }
            }
            LNAPPLY(g1r, be1r)
            #pragma unroll
            for (int kt = 0; kt < 4; kt++)
                A[kt] = *(const v8h*)&myslice[l15 * 136 + kt * 32 + quad * 8];
            #pragma unroll
            for (int nt = 0; nt < 8; nt++) {
                v4f ci = {b2r[nt], b2r[nt], b2r[nt], b2r[nt]};
                acc[nt] = ci;
            }
            #pragma unroll
            for (int kt = 0; kt < 4; kt++) {
                #pragma unroll
                for (int nt = 0; nt < 8; nt++) {
                    v8h Bv = *(const v8h*)&W2T[(nt * 16 + l15) * 136 + kt * 32 + quad * 8];
                    acc[nt] = MFMA16(A[kt], Bv, acc[nt]);
                }
            }
            LNAPPLY(g2r, be2r)
            // ---- qk_pos = p @ wqk + bqk (direct + mirror) ----
            {
                v4f c = {0.f, 0.f, 0.f, 0.f};
                #pragma unroll
                for (int kt = 0; kt < 4; kt++) {
                    v8h av = *(const v8h*)&myslice[l15 * 136 + kt * 32 + quad * 8];
                    v8h wq = *(const v8h*)&wqT[l15 * 136 + kt * 32 + quad * 8];
                    c = MFMA16(av, wq, c);
                }
                if (l15 < 4) {
                    #pragma unroll
                    for (int rg2 = 0; rg2 < 4; rg2++) {
                        int rowj = quad * 4 + rg2;
                        float val = c[rg2] + bqv;
                        qkpos[((long)(b * N_ + ii) * N_ + j0 + rowj) * 4 + l15] = val;
                        if (it != jt)
                            qkpos[((long)(b * N_ + j0 + rowj) * N_ + ii) * 4 + l15] = val;
                    }
                }
            }
        }
        __syncthreads();   // all 16 slices of this tile complete

        // ---- cooperative chunk writes: wave wv -> rows {2wv, 2wv+1} ----
        #pragma unroll
        for (int rx = 0; rx < 2; rx++) {
            const int r2 = wv * 2 + rx;
            // direct chunk: consumer row (b, it*16+r2), j-tile jt: [c][j16]
            {
                const _Float16* src = slices + r2 * 2176;
                _Float16* chunk = pT + (((long)(b * N_ + it * 16 + r2) * 24 + jt) << 11);
                #pragma unroll
                for (int cc = 0; cc < 2; cc++) {
                    int c = lane + cc * 64;
                    v8h lo, hi;
                    #pragma unroll
                    for (int k = 0; k < 8; k++) {
                        lo[k] = src[k * 136 + c];
                        hi[k] = src[(k + 8) * 136 + c];
                    }
                    *(v8h*)(chunk + c * 16)     = lo;
                    *(v8h*)(chunk + c * 16 + 8) = hi;
                }
            }
            // mirror chunk: consumer row (b, jt*16+r2), j-tile it: [c][i16]
            if (it != jt) {
                _Float16* chunk = pT + (((long)(b * N_ + jt * 16 + r2) * 24 + it) << 11);
                #pragma unroll
                for (int cc = 0; cc < 2; cc++) {
                    int c = lane + cc * 64;
                    v8h lo, hi;
                    #pragma unroll
                    for (int r = 0; r < 8; r++) {
                        lo[r] = slices[r * 2176 + r2 * 136 + c];
                        hi[r] = slices[(r + 8) * 2176 + r2 * 136 + c];
                    }
                    *(v8h*)(chunk + c * 16)     = lo;
                    *(v8h*)(chunk + c * 16 + 8) = hi;
                }
            }
        }
        __syncthreads();   // protect slices before next job
    }

    // ---- fused former K2b: blocks 88..135 (2-job blocks) do qk tiles ----
    {
        int gw = (blockIdx.x - 88) * 8 + wv;
        if (blockIdx.x >= 88 && gw < 384) {
            const int bh = gw / 48;
            const int rest = gw - bh * 48;
            const int it = rest >> 1, nh = rest & 1;
            const int bb = bh >> 2, hh = bh & 3;
            const int i0 = it * 16;
            v8h A0 = *(const v8h*)&qh[((long)(bh * N_) + i0 + l15) * DH_ + quad * 8];
            v8h A1 = *(const v8h*)&qh[((long)(bh * N_) + i0 + l15) * DH_ + 32 + quad * 8];
            #pragma unroll 1
            for (int nt = 0; nt < 12; nt++) {
                int jq0 = nh * 192 + nt * 16;
                v8h B0 = *(const v8h*)&kh[((long)(bh * N_) + jq0 + l15) * DH_ + quad * 8];
                v8h B1 = *(const v8h*)&kh[((long)(bh * N_) + jq0 + l15) * DH_ + 32 + quad * 8];
                v4f c = {0.f, 0.f, 0.f, 0.f};
                c = MFMA16(A0, B0, c);
                c = MFMA16(A1, B1, c);
                #pragma unroll
                for (int rg2 = 0; rg2 < 4; rg2++) {
                    int i = i0 + quad * 4 + rg2;
                    int j = jq0 + l15;
                    long idx = (((long)(bb * N_ + i)) * N_ + j) * 4 + hh;
                    qkq[idx] = c[rg2];
                }
            }
        }
    }
}

// ---------- K3A: per-pair edge-MLP (no barriers, streaming). cmi overwrites qkq in-place ----------
__global__ __launch_bounds__(256) void eq_k3a(
    const float* __restrict__ edges, const float* __restrict__ qkpos,
    float* __restrict__ qkq,
    const float* __restrict__ w_e1, const float* __restrict__ w_e2) {
    __shared__ _Float16 we1h[20 * 40];
    __shared__ float we2[40 * 4];
    const int t = threadIdx.x;
    for (int idx = t; idx < 800; idx += 256) we1h[idx] = (_Float16)w_e1[idx];
    if (t < 160) we2[t] = w_e2[t];
    __syncthreads();

    const long pair = (long)blockIdx.x * 256 + t;   // 294912 pairs = 1152 blocks
    float in20[20];
    {
        float4 qp = *(const float4*)(qkpos + pair * 4);
        float4 qq = *(const float4*)(qkq + pair * 4);
        in20[0] = qp.x + qq.x; in20[1] = qp.y + qq.y;
        in20[2] = qp.z + qq.z; in20[3] = qp.w + qq.w;
    }
    const float4* ep = (const float4*)(edges + pair * ED_);
    float4 e0 = ep[0], e1 = ep[1], e2 = ep[2], e3 = ep[3];
    in20[4] = e0.x;  in20[5] = e0.y;  in20[6] = e0.z;  in20[7] = e0.w;
    in20[8] = e1.x;  in20[9] = e1.y;  in20[10] = e1.z; in20[11] = e1.w;
    in20[12] = e2.x; in20[13] = e2.y; in20[14] = e2.z; in20[15] = e2.w;
    in20[16] = e3.x; in20[17] = e3.y; in20[18] = e3.z; in20[19] = e3.w;

    float c0 = 0, c1 = 0, c2 = 0, c3 = 0;
    #pragma unroll 1
    for (int oc = 0; oc < 5; oc++) {
        float a8[8] = {0.f, 0.f, 0.f, 0.f, 0.f, 0.f, 0.f, 0.f};
        #pragma unroll
        for (int c = 0; c < 20; c++) {
            float xc = in20[c];
            v8h wv = *(const v8h*)&we1h[c * 40 + oc * 8];   // 16B aligned: 80c + 16*oc
            #pragma unroll
            for (int o2 = 0; o2 < 8; o2++) a8[o2] += xc * (float)wv[o2];
        }
        #pragma unroll
        for (int o = 0; o < 8; o++) {
            float gg = gelu_(a8[o]);
            float4 w2v = *(const float4*)&we2[(oc * 8 + o) * 4];
            c0 += gg * w2v.x; c1 += gg * w2v.y; c2 += gg * w2v.z; c3 += gg * w2v.w;
        }
    }
    *(float4*)(qkq + pair * 4) = make_float4(c0, c1, c2, c3);
}

// ---------- K3B: softmax/coor-branch/ap(MFMA)/attn@v/out-proj (reads cmi) ----------
__global__ __launch_bounds__(384) void eq_k3b(
    const float* __restrict__ cmig,
    const _Float16* __restrict__ pT, const float* __restrict__ v,
    const float* __restrict__ coors,
    const float* __restrict__ w_c, const float* __restrict__ w_cg,
    const float* __restrict__ b_cg, const float* __restrict__ w_th,
    const float* __restrict__ cscale, const float* __restrict__ ccomb,
    const float* __restrict__ og, const float* __restrict__ rg,
    const float* __restrict__ w_vpos, const float* __restrict__ b_vpos,
    const float* __restrict__ w_out, const float* __restrict__ b_out,
    float* __restrict__ out0, float* __restrict__ out1) {
    int row = blockIdx.x;           // b*N + i
    int b = row / N_, i = row - b * N_;
    int j = threadIdx.x;            // 0..383
    __shared__ float wcs[16], wcgs[16], bcgs[4], wths[16];
    __shared__ float attnS[4 * N_];
    __shared__ float apS[2 * 4 * PD_];
    __shared__ float nodeS[256];
    __shared__ float4 red4[50];     // [0..31] reduce8 slots (base 0..3), [32..49] reduce12

    if (j < 16) { wcs[j] = w_c[j]; wcgs[j] = w_cg[j]; wths[j] = w_th[j]; }
    if (j < 4) bcgs[j] = b_cg[j];
    __syncthreads();

    // ---- cmi from K3A; derive gc/cp/rs ----
    long pair = ((long)row) * N_ + j;
    float4 cm = *(const float4*)(cmig + pair * 4);
    float cmi[4] = {cm.x, cm.y, cm.z, cm.w};
    float gc[4], cp[4], rs[4];
    #pragma unroll
    for (int h = 0; h < 4; h++) gc[h] = gelu_(cmi[h]);
    #pragma unroll
    for (int h = 0; h < 4; h++) {
        cp[h] = gc[0] * wcs[h] + gc[1] * wcs[4 + h] + gc[2] * wcs[8 + h] + gc[3] * wcs[12 + h];
        rs[h] = cmi[0] * wcgs[h] + cmi[1] * wcgs[4 + h] + cmi[2] * wcgs[8 + h] + cmi[3] * wcgs[12 + h] + bcgs[h];
    }

    // ---- fused reductions (2 barriers) + coordinate geometry ----
    float dx = coors[(b * N_ + i) * 3 + 0] - coors[(b * N_ + j) * 3 + 0];
    float dy = coors[(b * N_ + i) * 3 + 1] - coors[(b * N_ + j) * 3 + 1];
    float dz = coors[(b * N_ + i) * 3 + 2] - coors[(b * N_ + j) * 3 + 2];
    float nrm = sqrtf(dx * dx + dy * dy + dz * dz);
    float sc = cscale[0] * rcp_(fmaxf(nrm, 1e-8f));
    float rx = dx * sc, ry = dy * sc, rz = dz * sc;

    float4 m4  = make_float4(cmi[0], cmi[1], cmi[2], cmi[3]);
    float4 cm4 = make_float4(cp[0], cp[1], cp[2], cp[3]);
    block_reduce8(m4, cm4, true, red4, 0);
    float e[4], ec[4];
    e[0] = __expf(cmi[0] - m4.x); e[1] = __expf(cmi[1] - m4.y);
    e[2] = __expf(cmi[2] - m4.z); e[3] = __expf(cmi[3] - m4.w);
    ec[0] = __expf(cp[0] - cm4.x); ec[1] = __expf(cp[1] - cm4.y);
    ec[2] = __expf(cp[2] - cm4.z); ec[3] = __expf(cp[3] - cm4.w);
    float4 l4  = make_float4(e[0], e[1], e[2], e[3]);
    float4 cl4 = make_float4(ec[0], ec[1], ec[2], ec[3]);
    block_reduce8(l4, cl4, false, red4, 2);

    float sm[4] = {e[0] * rcp_(l4.x), e[1] * rcp_(l4.y), e[2] * rcp_(l4.z), e[3] * rcp_(l4.w)};
    #pragma unroll
    for (int h = 0; h < 4; h++)
        attnS[h * N_ + j] = wths[h * 4 + 0] * sm[0] + wths[h * 4 + 1] * sm[1]
                          + wths[h * 4 + 2] * sm[2] + wths[h * 4 + 3] * sm[3];

    float w[4] = {ec[0] * rcp_(cl4.x) * rs[0], ec[1] * rcp_(cl4.y) * rs[1],
                  ec[2] * rcp_(cl4.z) * rs[2], ec[3] * rcp_(cl4.w) * rs[3]};
    float rv[12];
    #pragma unroll
    for (int h = 0; h < 4; h++) { rv[h] = w[h] * rx; rv[4 + h] = w[h] * ry; rv[8 + h] = w[h] * rz; }
    #pragma unroll
    for (int o = 32; o > 0; o >>= 1) {
        #pragma unroll
        for (int k = 0; k < 12; k++) rv[k] += __shfl_xor(rv[k], o);
    }
    if ((j & 63) == 0) {
        int wid = j >> 6;
        red4[32 + wid * 3 + 0] = make_float4(rv[0], rv[1], rv[2], rv[3]);
        red4[32 + wid * 3 + 1] = make_float4(rv[4], rv[5], rv[6], rv[7]);
        red4[32 + wid * 3 + 2] = make_float4(rv[8], rv[9], rv[10], rv[11]);
    }
    __syncthreads();    // attnS + reduce12 ready
    if (j == 0) {
        float4 sx4 = red4[32], sy4 = red4[33], sz4 = red4[34];
        #pragma unroll
        for (int w2 = 1; w2 < 6; w2++) {
            float4 ax = red4[32 + w2 * 3 + 0], ay = red4[32 + w2 * 3 + 1], az = red4[32 + w2 * 3 + 2];
            sx4.x += ax.x; sx4.y += ax.y; sx4.z += ax.z; sx4.w += ax.w;
            sy4.x += ay.x; sy4.y += ay.y; sy4.z += ay.z; sy4.w += ay.w;
            sz4.x += az.x; sz4.y += az.y; sz4.z += az.z; sz4.w += az.w;
        }
        float f0 = ccomb[0] * rg[(b * H_ + 0) * N_ + i];
        float f1 = ccomb[1] * rg[(b * H_ + 1) * N_ + i];
        float f2 = ccomb[2] * rg[(b * H_ + 2) * N_ + i];
        float f3 = ccomb[3] * rg[(b * H_ + 3) * N_ + i];
        out1[(b * N_ + i) * 3 + 0] = f0 * sx4.x + f1 * sx4.y + f2 * sx4.z + f3 * sx4.w;
        out1[(b * N_ + i) * 3 + 1] = f0 * sy4.x + f1 * sy4.y + f2 * sy4.z + f3 * sy4.w;
        out1[(b * N_ + i) * 3 + 2] = f0 * sz4.x + f1 * sz4.y + f2 * sz4.z + f3 * sz4.w;
    }

    // ---- phase D: waves 0-1 -> ap via MFMA; threads 128..383 -> attn@v ----
    if (j < 128) {
        const int lane = j & 63, l15d = lane & 15, quadd = lane >> 4;
        const int parity = j >> 6;
        const int hh = l15d & 3;
        const float msk = (l15d < 4) ? 1.f : 0.f;
        v4f acc[8];
        #pragma unroll
        for (int nt = 0; nt < 8; nt++) { v4f z = {0.f, 0.f, 0.f, 0.f}; acc[nt] = z; }
        #pragma unroll 2
        for (int kth = 0; kth < 6; kth++) {
            int kt = parity * 6 + kth;
            float4 a0 = *(const float4*)&attnS[hh * N_ + kt * 32 + quadd * 8];
            float4 a1 = *(const float4*)&attnS[hh * N_ + kt * 32 + quadd * 8 + 4];
            v8h Af;
            Af[0] = (_Float16)(a0.x * msk); Af[1] = (_Float16)(a0.y * msk);
            Af[2] = (_Float16)(a0.z * msk); Af[3] = (_Float16)(a0.w * msk);
            Af[4] = (_Float16)(a1.x * msk); Af[5] = (_Float16)(a1.y * msk);
            Af[6] = (_Float16)(a1.z * msk); Af[7] = (_Float16)(a1.w * msk);
            const _Float16* chunkp = pT + (((long)row * 24 + kt * 2 + (quadd >> 1)) << 11)
                                        + ((quadd & 1) << 3);
            #pragma unroll
            for (int nt = 0; nt < 8; nt++) {
                v8h Bv = *(const v8h*)&chunkp[(nt * 16 + l15d) * 16];
                acc[nt] = MFMA16(Af, Bv, acc[nt]);
            }
        }
        if (quadd == 0) {
            #pragma unroll
            for (int nt = 0; nt < 8; nt++)
                #pragma unroll
                for (int rg2 = 0; rg2 < 4; rg2++)
                    apS[parity * 512 + rg2 * 128 + nt * 16 + l15d] = acc[nt][rg2];
        }
    } else {
        int tt = j - 128, h = tt >> 6, d = tt & 63;
        float acc0 = 0, acc1 = 0, acc2 = 0, acc3 = 0;
        const float* vp = v + ((long)(b * H_ + h) * N_) * DH_ + d;
        #pragma unroll 8
        for (int jj = 0; jj < N_; jj += 4) {
            float4 a = *(const float4*)&attnS[h * N_ + jj];
            acc0 += a.x * vp[(long)(jj + 0) * DH_];
            acc1 += a.y * vp[(long)(jj + 1) * DH_];
            acc2 += a.z * vp[(long)(jj + 2) * DH_];
            acc3 += a.w * vp[(long)(jj + 3) * DH_];
        }
        nodeS[tt] = (acc0 + acc1) + (acc2 + acc3);
    }
    __syncthreads();

    // ---- phase E: node = (attnv + ap@w_vpos + Sh*b_vpos) * out_gate ----
    // thread j reads and writes only nodeS[j] -> no barrier needed between
    if (j < 256) {
        int h = j >> 6, d = j & 63;
        float accp = 0;
        const float* wv = w_vpos + h * DH_ + d;
        #pragma unroll 4
        for (int c4 = 0; c4 < 32; c4++) {
            float4 p0 = *(const float4*)&apS[h * 128 + c4 * 4];
            float4 p1 = *(const float4*)&apS[512 + h * 128 + c4 * 4];
            accp += (p0.x + p1.x) * wv[(long)(c4 * 4 + 0) * (H_ * DH_)]
                  + (p0.y + p1.y) * wv[(long)(c4 * 4 + 1) * (H_ * DH_)]
                  + (p0.z + p1.z) * wv[(long)(c4 * 4 + 2) * (H_ * DH_)]
                  + (p0.w + p1.w) * wv[(long)(c4 * 4 + 3) * (H_ * DH_)];
        }
        float Sh = wths[h * 4 + 0] + wths[h * 4 + 1] + wths[h * 4 + 2] + wths[h * 4 + 3];
        nodeS[j] = (nodeS[j] + accp + Sh * b_vpos[h * DH_ + d]) * og[(b * H_ + h) * N_ + i];
    }
    __syncthreads();

    // ---- phase F: out0 = node @ w_out + b_out ----
    if (j < 256) {
        float acc = b_out[j];
        const float* wo = w_out + j;
        #pragma unroll 4
        for (int c4 = 0; c4 < 64; c4++) {
            float4 nv4 = *(const float4*)&nodeS[c4 * 4];
            acc += nv4.x * wo[(long)(c4 * 4 + 0) * 256]
                 + nv4.y * wo[(long)(c4 * 4 + 1) * 256]
                 + nv4.z * wo[(long)(c4 * 4 + 2) * 256]
                 + nv4.w * wo[(long)(c4 * 4 + 3) * 256];
        }
        out0[(long)row * 256 + j] = acc;
    }
}

extern "C" void kernel_launch(void* const* d_in, const int* in_sizes, int n_in,
                              void* d_out, int out_size, void* d_ws, size_t ws_size,
                              hipStream_t stream) {
    (void)in_sizes; (void)n_in; (void)out_size; (void)ws_size;
    const float* feats   = (const float*)d_in[0];
    const float* coors   = (const float*)d_in[1];
    const float* edges   = (const float*)d_in[2];
    const float* gamma   = (const float*)d_in[3];
    const float* w_qkv   = (const float*)d_in[4];
    const float* w_gate  = (const float*)d_in[5];
    const float* b_gate  = (const float*)d_in[6];
    const float* w_th    = (const float*)d_in[7];
    const float* w_e1    = (const float*)d_in[8];
    const float* w_e2    = (const float*)d_in[9];
    const float* w_c     = (const float*)d_in[10];
    const float* w_cg    = (const float*)d_in[11];
    const float* b_cg    = (const float*)d_in[12];
    const float* cscale  = (const float*)d_in[13];
    const float* ccomb   = (const float*)d_in[14];
    const float* pb_w0   = (const float*)d_in[15];
    const float* pb_b0   = (const float*)d_in[16];
    const float* pb_g0   = (const float*)d_in[17];
    const float* pb_be0  = (const float*)d_in[18];
    const float* pb_w1   = (const float*)d_in[19];
    const float* pb_b1   = (const float*)d_in[20];
    const float* pb_g1   = (const float*)d_in[21];
    const float* pb_be1  = (const float*)d_in[22];
    const float* pb_w2   = (const float*)d_in[23];
    const float* pb_b2   = (const float*)d_in[24];
    const float* pb_g2   = (const float*)d_in[25];
    const float* pb_be2  = (const float*)d_in[26];
    const float* w_qkpos = (const float*)d_in[27];
    const float* b_qkpos = (const float*)d_in[28];
    const float* w_vpos  = (const float*)d_in[29];
    const float* b_vpos  = (const float*)d_in[30];
    const float* w_out   = (const float*)d_in[31];
    const float* b_out   = (const float*)d_in[32];

    // workspace carve (bytes)
    char* ws = (char*)d_ws;
    _Float16* qh   = (_Float16*)(ws + 0);            // 393216 B
    _Float16* kh   = (_Float16*)(ws + 393216);       // 393216 B
    float* v       = (float*)(ws + 786432);          // 786432 B
    float* og      = (float*)(ws + 1572864);         // 12288 B
    float* rg      = (float*)(ws + 1585152);         // 12288 B
    float* qkpos   = (float*)(ws + 1597440);         // 4718592 B
    _Float16* pT   = (_Float16*)(ws + 6316032);      // 75497472 B (tiled chunks)
    float* qkq     = (float*)(ws + 81813504);        // 4718592 B (qk dot, then cmi in-place)

    float* out0 = (float*)d_out;
    float* out1 = out0 + (long)B_ * N_ * DIM_;

    const int K2_LDS = 145152;    // 16 slices: 75520 + 69632
    hipFuncSetAttribute((const void*)eq_k2, hipFuncAttributeMaxDynamicSharedMemorySize, K2_LDS);

    eq_k1<<<384, 256, 0, stream>>>(feats, gamma, w_qkv, w_gate, b_gate, qh, kh, v, og, rg);
    eq_k2<<<256, 512, K2_LDS, stream>>>(coors, pb_w0, pb_b0, pb_g0, pb_be0,
                                        pb_w1, pb_b1, pb_g1, pb_be1,
                                        pb_w2, pb_b2, pb_g2, pb_be2,
                                        w_qkpos, b_qkpos, qh, kh, pT, qkpos, qkq);
    eq_k3a<<<(B_ * N_ * N_) / 256, 256, 0, stream>>>(edges, qkpos, qkq, w_e1, w_e2);
    eq_k3b<<<B_ * N_, 384, 0, stream>>>(qkq, pT, v, coors,
                                        w_c, w_cg, b_cg, w_th,
                                        cscale, ccomb, og, rg,
                                        w_vpos, b_vpos, w_out, b_out, out0, out1);
}

// Round 19
// 271.599 us; speedup vs baseline: 1.1930x; 1.0344x over previous
//
#include <hip/hip_runtime.h>
#include <hip/hip_bf16.h>

#define B_   2
#define N_   384
#define DIM_ 256
#define H_   4
#define DH_  64
#define PD_  128
#define ED_  16
#define NT_  24                 // j-tiles per row (N_/16)
#define TPB_ 300                // upper-tri tiles per batch: 24*25/2
#define HJOBS_ 1200             // half-tile jobs: 2 per tile (B_*TPB_*2)

typedef _Float16 v8h __attribute__((ext_vector_type(8)));
typedef float    v4f __attribute__((ext_vector_type(4)));

__device__ __forceinline__ float rcp_(float x) { return __builtin_amdgcn_rcpf(x); }

// fast erf: Abramowitz-Stegun 7.1.26, |err| <= 1.5e-7 (rcp instead of IEEE div)
__device__ __forceinline__ float erf_fast(float x) {
    float ax = fabsf(x);
    float t = rcp_(fmaf(0.3275911f, ax, 1.0f));
    float y = t * fmaf(t, fmaf(t, fmaf(t, fmaf(t, 1.061405429f, -1.453152027f),
                                       1.421413741f), -0.284496736f), 0.254829592f);
    float r = 1.0f - y * __expf(-ax * ax);
    return (x < 0.f) ? -r : r;
}
__device__ __forceinline__ float gelu_(float x) {
    return 0.5f * x * (1.0f + erf_fast(x * 0.70710678118654752f));
}
__device__ __forceinline__ float silu_(float x) {
    return x * rcp_(1.0f + __expf(-x));
}

// batched float2 block reduction over 256 threads (4 waves)
__device__ __forceinline__ float2 block_reduce256_f2(float2 v, float2* red) {
    #pragma unroll
    for (int o = 32; o > 0; o >>= 1) {
        v.x += __shfl_xor(v.x, o); v.y += __shfl_xor(v.y, o);
    }
    __syncthreads();
    if ((threadIdx.x & 63) == 0) red[threadIdx.x >> 6] = v;
    __syncthreads();
    float2 r = red[0];
    #pragma unroll
    for (int w2 = 1; w2 < 4; w2++) {
        float2 o = red[w2];
        r.x += o.x; r.y += o.y;
    }
    return r;
}

// dual float4 block reduction over 384 threads (6 waves): one barrier for 8 values.
__device__ __forceinline__ void block_reduce8(float4& va, float4& vb, bool ismax,
                                              float4* red, int base) {
    #pragma unroll
    for (int o = 32; o > 0; o >>= 1) {
        float ax = __shfl_xor(va.x, o), ay = __shfl_xor(va.y, o);
        float az = __shfl_xor(va.z, o), aw = __shfl_xor(va.w, o);
        float bx = __shfl_xor(vb.x, o), by = __shfl_xor(vb.y, o);
        float bz = __shfl_xor(vb.z, o), bw = __shfl_xor(vb.w, o);
        if (ismax) {
            va.x = fmaxf(va.x, ax); va.y = fmaxf(va.y, ay); va.z = fmaxf(va.z, az); va.w = fmaxf(va.w, aw);
            vb.x = fmaxf(vb.x, bx); vb.y = fmaxf(vb.y, by); vb.z = fmaxf(vb.z, bz); vb.w = fmaxf(vb.w, bw);
        } else {
            va.x += ax; va.y += ay; va.z += az; va.w += aw;
            vb.x += bx; vb.y += by; vb.z += bz; vb.w += bw;
        }
    }
    if ((threadIdx.x & 63) == 0) {
        red[base * 8 + (threadIdx.x >> 6)]       = va;
        red[(base + 1) * 8 + (threadIdx.x >> 6)] = vb;
    }
    __syncthreads();
    va = red[base * 8]; vb = red[(base + 1) * 8];
    #pragma unroll
    for (int w2 = 1; w2 < 6; w2++) {
        float4 oa = red[base * 8 + w2], ob = red[(base + 1) * 8 + w2];
        if (ismax) {
            va.x = fmaxf(va.x, oa.x); va.y = fmaxf(va.y, oa.y); va.z = fmaxf(va.z, oa.z); va.w = fmaxf(va.w, oa.w);
            vb.x = fmaxf(vb.x, ob.x); vb.y = fmaxf(vb.y, ob.y); vb.z = fmaxf(vb.z, ob.z); vb.w = fmaxf(vb.w, ob.w);
        } else {
            va.x += oa.x; va.y += oa.y; va.z += oa.z; va.w += oa.w;
            vb.x += ob.x; vb.y += ob.y; vb.z += ob.z; vb.w += ob.w;
        }
    }
}

// ---------- K1: LayerNorm + QKV (2 rows/block -> 384 blocks, f16 q/k out) + gates ----------
__global__ __launch_bounds__(256) void eq_k1(
    const float* __restrict__ feats, const float* __restrict__ gamma,
    const float* __restrict__ w_qkv, const float* __restrict__ w_gate,
    const float* __restrict__ b_gate,
    _Float16* __restrict__ qh, _Float16* __restrict__ kh, float* __restrict__ v,
    float* __restrict__ og, float* __restrict__ rg) {
    const int r0 = blockIdx.x * 2;
    const int b = r0 / N_;
    const int t = threadIdx.x;
    __shared__ float xs[2][DIM_];
    __shared__ float2 red2k[4];
    __shared__ float gredS[16][17];
    float2 f;
    f.x = feats[(long)(r0 + 0) * DIM_ + t];
    f.y = feats[(long)(r0 + 1) * DIM_ + t];
    float2 s = block_reduce256_f2(f, red2k);
    float mx = s.x * (1.f/DIM_), my = s.y * (1.f/DIM_);
    float2 d = make_float2(f.x - mx, f.y - my);
    float2 vr = block_reduce256_f2(make_float2(d.x*d.x, d.y*d.y), red2k);
    float g = gamma[t];
    xs[0][t] = d.x * rsqrtf(vr.x * (1.f/DIM_) + 1e-5f) * g;
    xs[1][t] = d.y * rsqrtf(vr.y * (1.f/DIM_) + 1e-5f) * g;
    __syncthreads();
    float acc[6];
    #pragma unroll
    for (int k = 0; k < 6; k++) acc[k] = 0.f;
    for (int c = 0; c < DIM_; c++) {
        const float* wr = w_qkv + (long)c * 768;
        float w0 = wr[t], w1 = wr[t + 256], w2 = wr[t + 512];
        #pragma unroll
        for (int r = 0; r < 2; r++) {
            float xc = xs[r][c];
            acc[r * 3 + 0] += xc * w0;
            acc[r * 3 + 1] += xc * w1;
            acc[r * 3 + 2] += xc * w2;
        }
    }
    int h = t >> 6, dd = t & 63;
    #pragma unroll
    for (int r = 0; r < 2; r++) {
        int n = r0 + r - b * N_;
        long idx = ((long)(b * H_ + h) * N_ + n) * DH_ + dd;
        qh[idx] = (_Float16)(acc[r * 3 + 0] * 0.125f);     // dh^-0.5 pre-applied
        kh[idx] = (_Float16)(acc[r * 3 + 1]);
        v[idx]  = acc[r * 3 + 2];
    }
    // ---- gates: all 256 threads, 16 outputs x 16 chunks of 16 channels ----
    {
        const int o = t & 15, chunk = t >> 4;       // o: gg = o&7, rr = o>>3
        const int gg = o & 7, rr = o >> 3;
        float part = 0.f;
        #pragma unroll
        for (int k = 0; k < 16; k++) {
            int c = chunk * 16 + k;
            part += xs[rr][c] * w_gate[c * 8 + gg];
        }
        gredS[chunk][o] = part;
    }
    __syncthreads();
    if (t < 16) {
        float a = b_gate[t & 7];
        #pragma unroll
        for (int k = 0; k < 16; k++) a += gredS[k][t];
        float gv = rcp_(1.0f + __expf(-a));
        int rr2 = t >> 3, g2 = t & 7;
        int n = r0 + rr2 - b * N_;
        if (g2 < 4) og[(b * H_ + g2) * N_ + n] = gv;
        else        rg[(b * H_ + (g2 - 4)) * N_ + n] = gv;
    }
}

// ---------- K2: position-bias MLP (MFMA), SYMMETRY-HALVED, HALF-TILE JOBS ----------
// Jobs are half-tiles (8 i-rows): 1200 jobs / 256 blocks -> makespan 5
// half-jobs (2.5 tiles) vs 3 tiles before (-17% critical path). Each wave
// computes ONE row-unit per job; direct chunk written pre-barrier (own
// slice); mirror halves are disjoint 16B v8h stores (half 0 -> bytes
// [0,16), half 1 -> [16,32) of each [c] group) so the two half-jobs of a
// tile can run on different blocks race-free.
// LDS: 8 slices -> 110336 B total (base 75520 + 8*2176*2).
#define MFMA16(a, b, c) __builtin_amdgcn_mfma_f32_16x16x32_f16(a, b, c, 0, 0, 0)

#define LNAPPLY(gr_, ber_)                                                        \
{                                                                                  \
    _Pragma("unroll")                                                              \
    for (int rg2 = 0; rg2 < 4; rg2++) {                                            \
        float s = 0.f, sq = 0.f;                                                   \
        _Pragma("unroll")                                                          \
        for (int nt = 0; nt < 8; nt++) {                                           \
            float v0 = acc[nt][rg2]; s += v0; sq += v0 * v0;                       \
        }                                                                          \
        s += __shfl_xor(s, 1); sq += __shfl_xor(sq, 1);                            \
        s += __shfl_xor(s, 2); sq += __shfl_xor(sq, 2);                            \
        s += __shfl_xor(s, 4); sq += __shfl_xor(sq, 4);                            \
        s += __shfl_xor(s, 8); sq += __shfl_xor(sq, 8);                            \
        float mean = s * (1.f / 128.f);                                            \
        float inv = rsqrtf(sq * (1.f / 128.f) - mean * mean + 1e-5f);              \
        int row2 = quad * 4 + rg2;                                                 \
        _Pragma("unroll")                                                          \
        for (int nt = 0; nt < 8; nt++) {                                           \
            float y = (acc[nt][rg2] - mean) * inv * gr_[nt] + ber_[nt];            \
            myslice[row2 * 136 + nt * 16 + l15] = (_Float16)silu_(y);              \
        }                                                                          \
    }                                                                              \
}

__global__ __launch_bounds__(512) __attribute__((amdgpu_waves_per_eu(2, 2)))
void eq_k2(
    const float* __restrict__ coors,
    const float* __restrict__ w0, const float* __restrict__ b0,
    const float* __restrict__ g0, const float* __restrict__ be0,
    const float* __restrict__ W1g, const float* __restrict__ b1,
    const float* __restrict__ g1, const float* __restrict__ be1,
    const float* __restrict__ W2g, const float* __restrict__ b2,
    const float* __restrict__ g2, const float* __restrict__ be2,
    const float* __restrict__ wqk, const float* __restrict__ bqk,
    const _Float16* __restrict__ qh, const _Float16* __restrict__ kh,
    _Float16* __restrict__ pT, float* __restrict__ qkpos,
    float* __restrict__ qkq) {

    extern __shared__ char smem[];
    _Float16* W1T    = (_Float16*)smem;                   // 128x136 = 34816 B
    _Float16* W2T    = (_Float16*)(smem + 34816);         // 34816 B
    _Float16* wqT    = (_Float16*)(smem + 69632);         // 16x136 = 4352 B
    float*    PQR    = (float*)(smem + 73984);            // 1536 B
    _Float16* slices = (_Float16*)(smem + 75520);         // 8 x 16x136 = 34816 B
    // total 110336 B -> 1 block/CU (8 waves, 2/SIMD)

    const int t = threadIdx.x;
    const int lane = t & 63, wv = t >> 6;
    const int l15 = lane & 15, quad = lane >> 4;

    for (int idx = t; idx < 16384; idx += 512) {
        int k = idx >> 7, n = idx & 127;
        W1T[n * 136 + k] = (_Float16)W1g[idx];
        W2T[n * 136 + k] = (_Float16)W2g[idx];
    }
    for (int idx = t; idx < 2048; idx += 512) {
        int n = idx >> 7, k = idx & 127;
        wqT[n * 136 + k] = (n < 4) ? (_Float16)wqk[k * 4 + n] : (_Float16)0.f;
    }
    float Sw = 0, Sb = 0, Sww = 0, Swb = 0, Sbb = 0;
    for (int c = 0; c < 128; c++) {
        float w = w0[c], bb2v = b0[c];
        Sw += w; Sb += bb2v; Sww += w * w; Swb += w * bb2v; Sbb += bb2v * bb2v;
    }
    const float mw = Sw * (1.f / 128.f), mbb = Sb * (1.f / 128.f);
    const float A2 = Sww * (1.f / 128.f) - mw * mw;
    const float AD = Swb * (1.f / 128.f) - mw * mbb;
    const float D2 = Sbb * (1.f / 128.f) - mbb * mbb;
    if (t < 128) {
        PQR[t]       = (w0[t] - mw) * g0[t];
        PQR[128 + t] = (b0[t] - mbb) * g0[t];
        PQR[256 + t] = be0[t];
    }
    // loop-invariant per-lane channel params in registers (c = nt*16 + l15)
    float b1r[8], b2r[8], g1r[8], be1r[8], g2r[8], be2r[8];
    #pragma unroll
    for (int nt = 0; nt < 8; nt++) {
        int c = nt * 16 + l15;
        b1r[nt] = b1[c]; b2r[nt] = b2[c];
        g1r[nt] = g1[c]; be1r[nt] = be1[c];
        g2r[nt] = g2[c]; be2r[nt] = be2[c];
    }
    const float bqv = (l15 < 4) ? bqk[l15] : 0.f;
    __syncthreads();

    for (int jo = blockIdx.x; jo < HJOBS_; jo += 256) {
        // unrank half-job -> (b, it, jt, half) with it <= jt
        const int tile = jo >> 1, half = jo & 1;
        int b = tile / TPB_;
        int tt2 = tile - b * TPB_;
        int it = 0, rl = NT_;
        while (tt2 >= rl) { tt2 -= rl; it++; rl--; }
        const int jt = it + tt2;
        const int j0 = jt * 16;

        const int r = half * 8 + wv;          // row-within-tile 0..15
        const int ii = it * 16 + r;
        _Float16* myslice = slices + wv * 2176;
        {
            const float cix = coors[(b * N_ + ii) * 3 + 0];
            const float ciy = coors[(b * N_ + ii) * 3 + 1];
            const float ciz = coors[(b * N_ + ii) * 3 + 2];
            float tt, uu;
            {
                int j = j0 + l15;
                float dx = cix - coors[(b * N_ + j) * 3 + 0];
                float dy = ciy - coors[(b * N_ + j) * 3 + 1];
                float dz = ciz - coors[(b * N_ + j) * 3 + 2];
                float d = sqrtf(dx * dx + dy * dy + dz * dz);
                float var = (d * d) * A2 + 2.f * d * AD + D2;
                float inv = rsqrtf(var + 1e-5f);
                tt = d * inv; uu = inv;
            }
            // layer0 directly into A-fragments (float4 PQR reads, rcp silu)
            v8h A[4];
            #pragma unroll
            for (int kt = 0; kt < 4; kt++) {
                int base = kt * 32 + quad * 8;
                float4 Pa = *(const float4*)&PQR[base],       Pb = *(const float4*)&PQR[base + 4];
                float4 Qa = *(const float4*)&PQR[128 + base], Qb = *(const float4*)&PQR[128 + base + 4];
                float4 Ra = *(const float4*)&PQR[256 + base], Rb = *(const float4*)&PQR[256 + base + 4];
                float Pj[8] = {Pa.x, Pa.y, Pa.z, Pa.w, Pb.x, Pb.y, Pb.z, Pb.w};
                float Qj[8] = {Qa.x, Qa.y, Qa.z, Qa.w, Qb.x, Qb.y, Qb.z, Qb.w};
                float Rj[8] = {Ra.x, Ra.y, Ra.z, Ra.w, Rb.x, Rb.y, Rb.z, Rb.w};
                v8h av;
                #pragma unroll
                for (int jj = 0; jj < 8; jj++) {
                    float y = tt * Pj[jj] + uu * Qj[jj] + Rj[jj];
                    av[jj] = (_Float16)silu_(y);
                }
                A[kt] = av;
            }
            v4f acc[8];
            #pragma unroll
            for (int nt = 0; nt < 8; nt++) {
                v4f ci = {b1r[nt], b1r[nt], b1r[nt], b1r[nt]};
                acc[nt] = ci;
            }
            #pragma unroll
            for (int kt = 0; kt < 4; kt++) {
                #pragma unroll
                for (int nt = 0; nt < 8; nt++) {
                    v8h Bv = *(const v8h*)&W1T[(nt * 16 + l15) * 136 + kt * 32 + quad * 8];
                    acc[nt] = MFMA16(A[kt], Bv, acc[nt]);
                }
            }
            LNAPPLY(g1r, be1r)
            #pragma unroll
            for (int kt = 0; kt < 4; kt++)
                A[kt] = *(const v8h*)&myslice[l15 * 136 + kt * 32 + quad * 8];
            #pragma unroll
            for (int nt = 0; nt < 8; nt++) {
                v4f ci = {b2r[nt], b2r[nt], b2r[nt], b2r[nt]};
                acc[nt] = ci;
            }
            #pragma unroll
            for (int kt = 0; kt < 4; kt++) {
                #pragma unroll
                for (int nt = 0; nt < 8; nt++) {
                    v8h Bv = *(const v8h*)&W2T[(nt * 16 + l15) * 136 + kt * 32 + quad * 8];
                    acc[nt] = MFMA16(A[kt], Bv, acc[nt]);
                }
            }
            LNAPPLY(g2r, be2r)
            // ---- qk_pos = p @ wqk + bqk (direct + mirror) ----
            {
                v4f c = {0.f, 0.f, 0.f, 0.f};
                #pragma unroll
                for (int kt = 0; kt < 4; kt++) {
                    v8h av = *(const v8h*)&myslice[l15 * 136 + kt * 32 + quad * 8];
                    v8h wq = *(const v8h*)&wqT[l15 * 136 + kt * 32 + quad * 8];
                    c = MFMA16(av, wq, c);
                }
                if (l15 < 4) {
                    #pragma unroll
                    for (int rg2 = 0; rg2 < 4; rg2++) {
                        int rowj = quad * 4 + rg2;
                        float val = c[rg2] + bqv;
                        qkpos[((long)(b * N_ + ii) * N_ + j0 + rowj) * 4 + l15] = val;
                        if (it != jt)
                            qkpos[((long)(b * N_ + j0 + rowj) * N_ + ii) * 4 + l15] = val;
                    }
                }
            }
        }

        // ---- direct chunk (own slice, pre-barrier): row (b,ii), j-tile jt ----
        {
            _Float16* chunk = pT + (((long)(b * N_ + ii) * 24 + jt) << 11);
            #pragma unroll
            for (int cc = 0; cc < 2; cc++) {
                int c = lane + cc * 64;
                v8h lo, hi;
                #pragma unroll
                for (int k = 0; k < 8; k++) {
                    lo[k] = myslice[k * 136 + c];
                    hi[k] = myslice[(k + 8) * 136 + c];
                }
                *(v8h*)(chunk + c * 16)     = lo;
                *(v8h*)(chunk + c * 16 + 8) = hi;
            }
        }
        __syncthreads();   // all 8 slices of this half-tile complete

        // ---- mirror half-chunks: wave wv -> consumer rows {2wv, 2wv+1} ----
        if (it != jt) {
            #pragma unroll
            for (int rx = 0; rx < 2; rx++) {
                const int r2 = wv * 2 + rx;      // j-row within jt tile
                _Float16* chunk = pT + (((long)(b * N_ + jt * 16 + r2) * 24 + it) << 11);
                #pragma unroll
                for (int cc = 0; cc < 2; cc++) {
                    int c = lane + cc * 64;
                    v8h m;
                    #pragma unroll
                    for (int k = 0; k < 8; k++)
                        m[k] = slices[k * 2176 + r2 * 136 + c];
                    *(v8h*)(chunk + c * 16 + half * 8) = m;
                }
            }
        }
        __syncthreads();   // protect slices before next job
    }

    // ---- fused qk tiles: blocks 176..223 (4-job blocks, 1 half-job slack) ----
    {
        int gw = (blockIdx.x - 176) * 8 + wv;
        if (blockIdx.x >= 176 && blockIdx.x < 224 && gw < 384) {
            const int bh = gw / 48;
            const int rest = gw - bh * 48;
            const int it = rest >> 1, nh = rest & 1;
            const int bb = bh >> 2, hh = bh & 3;
            const int i0 = it * 16;
            v8h A0 = *(const v8h*)&qh[((long)(bh * N_) + i0 + l15) * DH_ + quad * 8];
            v8h A1 = *(const v8h*)&qh[((long)(bh * N_) + i0 + l15) * DH_ + 32 + quad * 8];
            #pragma unroll 1
            for (int nt = 0; nt < 12; nt++) {
                int jq0 = nh * 192 + nt * 16;
                v8h B0 = *(const v8h*)&kh[((long)(bh * N_) + jq0 + l15) * DH_ + quad * 8];
                v8h B1 = *(const v8h*)&kh[((long)(bh * N_) + jq0 + l15) * DH_ + 32 + quad * 8];
                v4f c = {0.f, 0.f, 0.f, 0.f};
                c = MFMA16(A0, B0, c);
                c = MFMA16(A1, B1, c);
                #pragma unroll
                for (int rg2 = 0; rg2 < 4; rg2++) {
                    int i = i0 + quad * 4 + rg2;
                    int j = jq0 + l15;
                    long idx = (((long)(bb * N_ + i)) * N_ + j) * 4 + hh;
                    qkq[idx] = c[rg2];
                }
            }
        }
    }
}

// ---------- K3A: per-pair edge-MLP (no barriers, streaming). cmi overwrites qkq in-place ----------
__global__ __launch_bounds__(256) void eq_k3a(
    const float* __restrict__ edges, const float* __restrict__ qkpos,
    float* __restrict__ qkq,
    const float* __restrict__ w_e1, const float* __restrict__ w_e2) {
    __shared__ _Float16 we1h[20 * 40];
    __shared__ float we2[40 * 4];
    const int t = threadIdx.x;
    for (int idx = t; idx < 800; idx += 256) we1h[idx] = (_Float16)w_e1[idx];
    if (t < 160) we2[t] = w_e2[t];
    __syncthreads();

    const long pair = (long)blockIdx.x * 256 + t;   // 294912 pairs = 1152 blocks
    float in20[20];
    {
        float4 qp = *(const float4*)(qkpos + pair * 4);
        float4 qq = *(const float4*)(qkq + pair * 4);
        in20[0] = qp.x + qq.x; in20[1] = qp.y + qq.y;
        in20[2] = qp.z + qq.z; in20[3] = qp.w + qq.w;
    }
    const float4* ep = (const float4*)(edges + pair * ED_);
    float4 e0 = ep[0], e1 = ep[1], e2 = ep[2], e3 = ep[3];
    in20[4] = e0.x;  in20[5] = e0.y;  in20[6] = e0.z;  in20[7] = e0.w;
    in20[8] = e1.x;  in20[9] = e1.y;  in20[10] = e1.z; in20[11] = e1.w;
    in20[12] = e2.x; in20[13] = e2.y; in20[14] = e2.z; in20[15] = e2.w;
    in20[16] = e3.x; in20[17] = e3.y; in20[18] = e3.z; in20[19] = e3.w;

    float c0 = 0, c1 = 0, c2 = 0, c3 = 0;
    #pragma unroll 1
    for (int oc = 0; oc < 5; oc++) {
        float a8[8] = {0.f, 0.f, 0.f, 0.f, 0.f, 0.f, 0.f, 0.f};
        #pragma unroll
        for (int c = 0; c < 20; c++) {
            float xc = in20[c];
            v8h wv = *(const v8h*)&we1h[c * 40 + oc * 8];   // 16B aligned: 80c + 16*oc
            #pragma unroll
            for (int o2 = 0; o2 < 8; o2++) a8[o2] += xc * (float)wv[o2];
        }
        #pragma unroll
        for (int o = 0; o < 8; o++) {
            float gg = gelu_(a8[o]);
            float4 w2v = *(const float4*)&we2[(oc * 8 + o) * 4];
            c0 += gg * w2v.x; c1 += gg * w2v.y; c2 += gg * w2v.z; c3 += gg * w2v.w;
        }
    }
    *(float4*)(qkq + pair * 4) = make_float4(c0, c1, c2, c3);
}

// ---------- K3B: softmax/coor-branch/ap(MFMA)/attn@v/out-proj (reads cmi) ----------
__global__ __launch_bounds__(384) void eq_k3b(
    const float* __restrict__ cmig,
    const _Float16* __restrict__ pT, const float* __restrict__ v,
    const float* __restrict__ coors,
    const float* __restrict__ w_c, const float* __restrict__ w_cg,
    const float* __restrict__ b_cg, const float* __restrict__ w_th,
    const float* __restrict__ cscale, const float* __restrict__ ccomb,
    const float* __restrict__ og, const float* __restrict__ rg,
    const float* __restrict__ w_vpos, const float* __restrict__ b_vpos,
    const float* __restrict__ w_out, const float* __restrict__ b_out,
    float* __restrict__ out0, float* __restrict__ out1) {
    int row = blockIdx.x;           // b*N + i
    int b = row / N_, i = row - b * N_;
    int j = threadIdx.x;            // 0..383
    __shared__ float wcs[16], wcgs[16], bcgs[4], wths[16];
    __shared__ float attnS[4 * N_];
    __shared__ float apS[2 * 4 * PD_];
    __shared__ float nodeS[256];
    __shared__ float4 red4[50];     // [0..31] reduce8 slots (base 0..3), [32..49] reduce12

    if (j < 16) { wcs[j] = w_c[j]; wcgs[j] = w_cg[j]; wths[j] = w_th[j]; }
    if (j < 4) bcgs[j] = b_cg[j];
    __syncthreads();

    // ---- cmi from K3A; derive gc/cp/rs ----
    long pair = ((long)row) * N_ + j;
    float4 cm = *(const float4*)(cmig + pair * 4);
    float cmi[4] = {cm.x, cm.y, cm.z, cm.w};
    float gc[4], cp[4], rs[4];
    #pragma unroll
    for (int h = 0; h < 4; h++) gc[h] = gelu_(cmi[h]);
    #pragma unroll
    for (int h = 0; h < 4; h++) {
        cp[h] = gc[0] * wcs[h] + gc[1] * wcs[4 + h] + gc[2] * wcs[8 + h] + gc[3] * wcs[12 + h];
        rs[h] = cmi[0] * wcgs[h] + cmi[1] * wcgs[4 + h] + cmi[2] * wcgs[8 + h] + cmi[3] * wcgs[12 + h] + bcgs[h];
    }

    // ---- fused reductions (2 barriers) + coordinate geometry ----
    float dx = coors[(b * N_ + i) * 3 + 0] - coors[(b * N_ + j) * 3 + 0];
    float dy = coors[(b * N_ + i) * 3 + 1] - coors[(b * N_ + j) * 3 + 1];
    float dz = coors[(b * N_ + i) * 3 + 2] - coors[(b * N_ + j) * 3 + 2];
    float nrm = sqrtf(dx * dx + dy * dy + dz * dz);
    float sc = cscale[0] * rcp_(fmaxf(nrm, 1e-8f));
    float rx = dx * sc, ry = dy * sc, rz = dz * sc;

    float4 m4  = make_float4(cmi[0], cmi[1], cmi[2], cmi[3]);
    float4 cm4 = make_float4(cp[0], cp[1], cp[2], cp[3]);
    block_reduce8(m4, cm4, true, red4, 0);
    float e[4], ec[4];
    e[0] = __expf(cmi[0] - m4.x); e[1] = __expf(cmi[1] - m4.y);
    e[2] = __expf(cmi[2] - m4.z); e[3] = __expf(cmi[3] - m4.w);
    ec[0] = __expf(cp[0] - cm4.x); ec[1] = __expf(cp[1] - cm4.y);
    ec[2] = __expf(cp[2] - cm4.z); ec[3] = __expf(cp[3] - cm4.w);
    float4 l4  = make_float4(e[0], e[1], e[2], e[3]);
    float4 cl4 = make_float4(ec[0], ec[1], ec[2], ec[3]);
    block_reduce8(l4, cl4, false, red4, 2);

    float sm[4] = {e[0] * rcp_(l4.x), e[1] * rcp_(l4.y), e[2] * rcp_(l4.z), e[3] * rcp_(l4.w)};
    #pragma unroll
    for (int h = 0; h < 4; h++)
        attnS[h * N_ + j] = wths[h * 4 + 0] * sm[0] + wths[h * 4 + 1] * sm[1]
                          + wths[h * 4 + 2] * sm[2] + wths[h * 4 + 3] * sm[3];

    float w[4] = {ec[0] * rcp_(cl4.x) * rs[0], ec[1] * rcp_(cl4.y) * rs[1],
                  ec[2] * rcp_(cl4.z) * rs[2], ec[3] * rcp_(cl4.w) * rs[3]};
    float rv[12];
    #pragma unroll
    for (int h = 0; h < 4; h++) { rv[h] = w[h] * rx; rv[4 + h] = w[h] * ry; rv[8 + h] = w[h] * rz; }
    #pragma unroll
    for (int o = 32; o > 0; o >>= 1) {
        #pragma unroll
        for (int k = 0; k < 12; k++) rv[k] += __shfl_xor(rv[k], o);
    }
    if ((j & 63) == 0) {
        int wid = j >> 6;
        red4[32 + wid * 3 + 0] = make_float4(rv[0], rv[1], rv[2], rv[3]);
        red4[32 + wid * 3 + 1] = make_float4(rv[4], rv[5], rv[6], rv[7]);
        red4[32 + wid * 3 + 2] = make_float4(rv[8], rv[9], rv[10], rv[11]);
    }
    __syncthreads();    // attnS + reduce12 ready
    if (j == 0) {
        float4 sx4 = red4[32], sy4 = red4[33], sz4 = red4[34];
        #pragma unroll
        for (int w2 = 1; w2 < 6; w2++) {
            float4 ax = red4[32 + w2 * 3 + 0], ay = red4[32 + w2 * 3 + 1], az = red4[32 + w2 * 3 + 2];
            sx4.x += ax.x; sx4.y += ax.y; sx4.z += ax.z; sx4.w += ax.w;
            sy4.x += ay.x; sy4.y += ay.y; sy4.z += ay.z; sy4.w += ay.w;
            sz4.x += az.x; sz4.y += az.y; sz4.z += az.z; sz4.w += az.w;
        }
        float f0 = ccomb[0] * rg[(b * H_ + 0) * N_ + i];
        float f1 = ccomb[1] * rg[(b * H_ + 1) * N_ + i];
        float f2 = ccomb[2] * rg[(b * H_ + 2) * N_ + i];
        float f3 = ccomb[3] * rg[(b * H_ + 3) * N_ + i];
        out1[(b * N_ + i) * 3 + 0] = f0 * sx4.x + f1 * sx4.y + f2 * sx4.z + f3 * sx4.w;
        out1[(b * N_ + i) * 3 + 1] = f0 * sy4.x + f1 * sy4.y + f2 * sy4.z + f3 * sy4.w;
        out1[(b * N_ + i) * 3 + 2] = f0 * sz4.x + f1 * sz4.y + f2 * sz4.z + f3 * sz4.w;
    }

    // ---- phase D: waves 0-1 -> ap via MFMA; threads 128..383 -> attn@v ----
    if (j < 128) {
        const int lane = j & 63, l15d = lane & 15, quadd = lane >> 4;
        const int parity = j >> 6;
        const int hh = l15d & 3;
        const float msk = (l15d < 4) ? 1.f : 0.f;
        v4f acc[8];
        #pragma unroll
        for (int nt = 0; nt < 8; nt++) { v4f z = {0.f, 0.f, 0.f, 0.f}; acc[nt] = z; }
        #pragma unroll 2
        for (int kth = 0; kth < 6; kth++) {
            int kt = parity * 6 + kth;
            float4 a0 = *(const float4*)&attnS[hh * N_ + kt * 32 + quadd * 8];
            float4 a1 = *(const float4*)&attnS[hh * N_ + kt * 32 + quadd * 8 + 4];
            v8h Af;
            Af[0] = (_Float16)(a0.x * msk); Af[1] = (_Float16)(a0.y * msk);
            Af[2] = (_Float16)(a0.z * msk); Af[3] = (_Float16)(a0.w * msk);
            Af[4] = (_Float16)(a1.x * msk); Af[5] = (_Float16)(a1.y * msk);
            Af[6] = (_Float16)(a1.z * msk); Af[7] = (_Float16)(a1.w * msk);
            const _Float16* chunkp = pT + (((long)row * 24 + kt * 2 + (quadd >> 1)) << 11)
                                        + ((quadd & 1) << 3);
            #pragma unroll
            for (int nt = 0; nt < 8; nt++) {
                v8h Bv = *(const v8h*)&chunkp[(nt * 16 + l15d) * 16];
                acc[nt] = MFMA16(Af, Bv, acc[nt]);
            }
        }
        if (quadd == 0) {
            #pragma unroll
            for (int nt = 0; nt < 8; nt++)
                #pragma unroll
                for (int rg2 = 0; rg2 < 4; rg2++)
                    apS[parity * 512 + rg2 * 128 + nt * 16 + l15d] = acc[nt][rg2];
        }
    } else {
        int tt = j - 128, h = tt >> 6, d = tt & 63;
        float acc0 = 0, acc1 = 0, acc2 = 0, acc3 = 0;
        const float* vp = v + ((long)(b * H_ + h) * N_) * DH_ + d;
        #pragma unroll 8
        for (int jj = 0; jj < N_; jj += 4) {
            float4 a = *(const float4*)&attnS[h * N_ + jj];
            acc0 += a.x * vp[(long)(jj + 0) * DH_];
            acc1 += a.y * vp[(long)(jj + 1) * DH_];
            acc2 += a.z * vp[(long)(jj + 2) * DH_];
            acc3 += a.w * vp[(long)(jj + 3) * DH_];
        }
        nodeS[tt] = (acc0 + acc1) + (acc2 + acc3);
    }
    __syncthreads();

    // ---- phase E: node = (attnv + ap@w_vpos + Sh*b_vpos) * out_gate ----
    // thread j reads and writes only nodeS[j] -> no barrier needed between
    if (j < 256) {
        int h = j >> 6, d = j & 63;
        float accp = 0;
        const float* wv = w_vpos + h * DH_ + d;
        #pragma unroll 4
        for (int c4 = 0; c4 < 32; c4++) {
            float4 p0 = *(const float4*)&apS[h * 128 + c4 * 4];
            float4 p1 = *(const float4*)&apS[512 + h * 128 + c4 * 4];
            accp += (p0.x + p1.x) * wv[(long)(c4 * 4 + 0) * (H_ * DH_)]
                  + (p0.y + p1.y) * wv[(long)(c4 * 4 + 1) * (H_ * DH_)]
                  + (p0.z + p1.z) * wv[(long)(c4 * 4 + 2) * (H_ * DH_)]
                  + (p0.w + p1.w) * wv[(long)(c4 * 4 + 3) * (H_ * DH_)];
        }
        float Sh = wths[h * 4 + 0] + wths[h * 4 + 1] + wths[h * 4 + 2] + wths[h * 4 + 3];
        nodeS[j] = (nodeS[j] + accp + Sh * b_vpos[h * DH_ + d]) * og[(b * H_ + h) * N_ + i];
    }
    __syncthreads();

    // ---- phase F: out0 = node @ w_out + b_out ----
    if (j < 256) {
        float acc = b_out[j];
        const float* wo = w_out + j;
        #pragma unroll 4
        for (int c4 = 0; c4 < 64; c4++) {
            float4 nv4 = *(const float4*)&nodeS[c4 * 4];
            acc += nv4.x * wo[(long)(c4 * 4 + 0) * 256]
                 + nv4.y * wo[(long)(c4 * 4 + 1) * 256]
                 + nv4.z * wo[(long)(c4 * 4 + 2) * 256]
                 + nv4.w * wo[(long)(c4 * 4 + 3) * 256];
        }
        out0[(long)row * 256 + j] = acc;
    }
}

extern "C" void kernel_launch(void* const* d_in, const int* in_sizes, int n_in,
                              void* d_out, int out_size, void* d_ws, size_t ws_size,
                              hipStream_t stream) {
    (void)in_sizes; (void)n_in; (void)out_size; (void)ws_size;
    const float* feats   = (const float*)d_in[0];
    const float* coors   = (const float*)d_in[1];
    const float* edges   = (const float*)d_in[2];
    const float* gamma   = (const float*)d_in[3];
    const float* w_qkv   = (const float*)d_in[4];
    const float* w_gate  = (const float*)d_in[5];
    const float* b_gate  = (const float*)d_in[6];
    const float* w_th    = (const float*)d_in[7];
    const float* w_e1    = (const float*)d_in[8];
    const float* w_e2    = (const float*)d_in[9];
    const float* w_c     = (const float*)d_in[10];
    const float* w_cg    = (const float*)d_in[11];
    const float* b_cg    = (const float*)d_in[12];
    const float* cscale  = (const float*)d_in[13];
    const float* ccomb   = (const float*)d_in[14];
    const float* pb_w0   = (const float*)d_in[15];
    const float* pb_b0   = (const float*)d_in[16];
    const float* pb_g0   = (const float*)d_in[17];
    const float* pb_be0  = (const float*)d_in[18];
    const float* pb_w1   = (const float*)d_in[19];
    const float* pb_b1   = (const float*)d_in[20];
    const float* pb_g1   = (const float*)d_in[21];
    const float* pb_be1  = (const float*)d_in[22];
    const float* pb_w2   = (const float*)d_in[23];
    const float* pb_b2   = (const float*)d_in[24];
    const float* pb_g2   = (const float*)d_in[25];
    const float* pb_be2  = (const float*)d_in[26];
    const float* w_qkpos = (const float*)d_in[27];
    const float* b_qkpos = (const float*)d_in[28];
    const float* w_vpos  = (const float*)d_in[29];
    const float* b_vpos  = (const float*)d_in[30];
    const float* w_out   = (const float*)d_in[31];
    const float* b_out   = (const float*)d_in[32];

    // workspace carve (bytes)
    char* ws = (char*)d_ws;
    _Float16* qh   = (_Float16*)(ws + 0);            // 393216 B
    _Float16* kh   = (_Float16*)(ws + 393216);       // 393216 B
    float* v       = (float*)(ws + 786432);          // 786432 B
    float* og      = (float*)(ws + 1572864);         // 12288 B
    float* rg      = (float*)(ws + 1585152);         // 12288 B
    float* qkpos   = (float*)(ws + 1597440);         // 4718592 B
    _Float16* pT   = (_Float16*)(ws + 6316032);      // 75497472 B (tiled chunks)
    float* qkq     = (float*)(ws + 81813504);        // 4718592 B (qk dot, then cmi in-place)

    float* out0 = (float*)d_out;
    float* out1 = out0 + (long)B_ * N_ * DIM_;

    const int K2_LDS = 110336;    // 8 slices: 75520 + 34816 (matches kernel layout)
    hipFuncSetAttribute((const void*)eq_k2, hipFuncAttributeMaxDynamicSharedMemorySize, K2_LDS);

    eq_k1<<<384, 256, 0, stream>>>(feats, gamma, w_qkv, w_gate, b_gate, qh, kh, v, og, rg);
    eq_k2<<<256, 512, K2_LDS, stream>>>(coors, pb_w0, pb_b0, pb_g0, pb_be0,
                                        pb_w1, pb_b1, pb_g1, pb_be1,
                                        pb_w2, pb_b2, pb_g2, pb_be2,
                                        w_qkpos, b_qkpos, qh, kh, pT, qkpos, qkq);
    eq_k3a<<<(B_ * N_ * N_) / 256, 256, 0, stream>>>(edges, qkpos, qkq, w_e1, w_e2);
    eq_k3b<<<B_ * N_, 384, 0, stream>>>(qkq, pT, v, coors,
                                        w_c, w_cg, b_cg, w_th,
                                        cscale, ccomb, og, rg,
                                        w_vpos, b_vpos, w_out, b_out, out0, out1);
}